// Round 1
// baseline (471.199 us; speedup 1.0000x reference)
//
#include <hip/hip_runtime.h>
#include <math.h>

namespace {
constexpr int Bn = 4, Cin = 64, Cout = 64, Hh = 128, Ww = 128, Ho = 126, Wo = 126;
constexpr int Npix = Bn * Ho * Wo;          // 63504
constexpr int HW = Hh * Ww;                 // 16384
constexpr int PixPerImg = Ho * Wo;          // 15876
}

// ---------------------------------------------------------------------------
// prep: transpose weights so the hot loops read them with wave-uniform
// (scalar) addresses.
//   w_off_t[cin*243 + k*27 + o]      = w_off[o,cin,kh,kw]   (15552 floats)
//   w_t[(k*64+cin)*64 + cout]        = weight[cout,cin,kh,kw] (36864 floats)
// ---------------------------------------------------------------------------
__global__ __launch_bounds__(256) void prep_kernel(
    const float* __restrict__ w_off, const float* __restrict__ weight,
    float* __restrict__ w_off_t, float* __restrict__ w_t)
{
    int i = blockIdx.x * 256 + threadIdx.x;
    if (i < 27 * 64 * 9) {
        int o = i % 27, t = i / 27, k = t % 9, cin = t / 9;
        w_off_t[i] = w_off[o * (64 * 9) + cin * 9 + k];
    }
    if (i < 64 * 64 * 9) {
        int cout = i % 64, t = i / 64, cin = t % 64, k = t / 64;
        w_t[i] = weight[cout * (64 * 9) + cin * 9 + k];
    }
}

// ---------------------------------------------------------------------------
// offset conv (3x3 VALID, 64->27) + coordinate/mask computation.
// lane = pixel; each lane accumulates all 27 channels; weights are scalar.
// Output planes A_off[27][Npix]:
//   j in [0,9):  ys_j = ho + j/3 + off_y_j          (off_y_j = conv ch 2j)
//   j in [9,18): xs_j = wo + j%3 + off_x_j          (off_x_j = conv ch 2j+1)
//   j in [18,27): sigmoid(conv ch j)                (mask)
// ---------------------------------------------------------------------------
__global__ __launch_bounds__(256) void offconv_kernel(
    const float* __restrict__ x, const float* __restrict__ w_off_t,
    const float* __restrict__ b_off, float* __restrict__ A_off)
{
    int wid  = __builtin_amdgcn_readfirstlane((int)(threadIdx.x >> 6));
    int lane = (int)(threadIdx.x & 63);
    int gw = blockIdx.x * 4 + wid;
    int p  = gw * 64 + lane;
    bool active = p < Npix;
    int pc = active ? p : (Npix - 1);
    int b  = pc / PixPerImg;
    int r  = pc - b * PixPerImg;
    int ho = r / Wo;
    int wo = r - ho * Wo;

    float acc[27];
#pragma unroll
    for (int o = 0; o < 27; ++o) acc[o] = 0.f;

    const float* xp = x + b * (Cin * HW) + ho * Ww + wo;
    for (int cin = 0; cin < Cin; ++cin) {
        float xv[9];
#pragma unroll
        for (int kh = 0; kh < 3; ++kh)
#pragma unroll
            for (int kw = 0; kw < 3; ++kw)
                xv[kh * 3 + kw] = xp[cin * HW + kh * Ww + kw];
        const float* wt = w_off_t + cin * 243;
#pragma unroll
        for (int k = 0; k < 9; ++k) {
            float xk = xv[k];
#pragma unroll
            for (int o = 0; o < 27; ++o)
                acc[o] = fmaf(xk, wt[k * 27 + o], acc[o]);
        }
    }
    if (!active) return;
#pragma unroll
    for (int j = 0; j < 9; ++j) {
        float ys = (float)(ho + j / 3) + acc[2 * j]     + b_off[2 * j];
        float xs = (float)(wo + j % 3) + acc[2 * j + 1] + b_off[2 * j + 1];
        float mv = acc[18 + j] + b_off[18 + j];
        float m  = 1.0f / (1.0f + expf(-mv));
        A_off[j * Npix + p]        = ys;
        A_off[(9 + j) * Npix + p]  = xs;
        A_off[(18 + j) * Npix + p] = m;
    }
}

// ---------------------------------------------------------------------------
// main deformable conv: lane = pixel, wave covers 64 pixels x 32 couts
// (cout split in half across wave pairs for grid parallelism).
// Bilinear validity+mask folded into 4 corner weights (branchless).
// Weight stream is wave-uniform -> scalar loads.
// ---------------------------------------------------------------------------
__global__ __launch_bounds__(256) void mdconv_kernel(
    const float* __restrict__ x, const float* __restrict__ A_off,
    const float* __restrict__ w_t, const float* __restrict__ bias,
    float* __restrict__ out)
{
    int wid  = __builtin_amdgcn_readfirstlane((int)(threadIdx.x >> 6));
    int lane = (int)(threadIdx.x & 63);
    int gw   = blockIdx.x * 4 + wid;
    int pw   = gw >> 1;
    int half = gw & 1;
    int p    = pw * 64 + lane;
    bool active = p < Npix;
    int pc = active ? p : (Npix - 1);
    int b  = pc / PixPerImg;
    int r  = pc - b * PixPerImg;
    int ho = r / Wo;
    int wo = r - ho * Wo;

    float acc[32];
#pragma unroll
    for (int c = 0; c < 32; ++c) acc[c] = 0.f;

    const float* xb = x + b * (Cin * HW);

    for (int k = 0; k < 9; ++k) {
        float ys = A_off[k * Npix + pc];
        float xs = A_off[(9 + k) * Npix + pc];
        float m  = A_off[(18 + k) * Npix + pc];
        float y0f = floorf(ys), x0f = floorf(xs);
        float wy = ys - y0f, wx = xs - x0f;
        int y0 = (int)y0f, x0 = (int)x0f;
        float vy0 = (y0 >= 0  && y0 < Hh)     ? 1.f : 0.f;
        float vy1 = (y0 >= -1 && y0 < Hh - 1) ? 1.f : 0.f;
        float vx0 = (x0 >= 0  && x0 < Ww)     ? 1.f : 0.f;
        float vx1 = (x0 >= -1 && x0 < Ww - 1) ? 1.f : 0.f;
        int y0c = min(max(y0, 0), Hh - 1);
        int y1c = min(max(y0 + 1, 0), Hh - 1);
        int x0c = min(max(x0, 0), Ww - 1);
        int x1c = min(max(x0 + 1, 0), Ww - 1);
        float w00 = (1.f - wy) * (1.f - wx) * m * vy0 * vx0;
        float w01 = (1.f - wy) * wx         * m * vy0 * vx1;
        float w10 = wy         * (1.f - wx) * m * vy1 * vx0;
        float w11 = wy         * wx         * m * vy1 * vx1;
        int a00 = y0c * Ww + x0c, a01 = y0c * Ww + x1c;
        int a10 = y1c * Ww + x0c, a11 = y1c * Ww + x1c;
        const float* wk = w_t + k * (64 * 64) + half * 32;
#pragma unroll 4
        for (int cin = 0; cin < Cin; ++cin) {
            const float* xc = xb + cin * HW;
            float v00 = xc[a00], v01 = xc[a01], v10 = xc[a10], v11 = xc[a11];
            float s = w00 * v00 + w01 * v01;
            s = fmaf(w10, v10, s);
            s = fmaf(w11, v11, s);
            const float* wr = wk + cin * 64;
#pragma unroll
            for (int co = 0; co < 32; ++co)
                acc[co] = fmaf(s, wr[co], acc[co]);
        }
    }
    if (!active) return;
    const int cbase = half * 32;
#pragma unroll
    for (int co = 0; co < 32; ++co) {
        float v = acc[co] + bias[cbase + co];
        out[((b * Cout + cbase + co) * Ho + ho) * Wo + wo] = fmaxf(v, 0.f);
    }
}

extern "C" void kernel_launch(void* const* d_in, const int* in_sizes, int n_in,
                              void* d_out, int out_size, void* d_ws, size_t ws_size,
                              hipStream_t stream)
{
    const float* x      = (const float*)d_in[0];
    const float* w_off  = (const float*)d_in[1];
    const float* b_off  = (const float*)d_in[2];
    const float* weight = (const float*)d_in[3];
    const float* bias   = (const float*)d_in[4];

    float* ws       = (float*)d_ws;
    float* w_off_t  = ws;                        // 15552 floats
    float* w_t      = ws + 15552;                // 36864 floats
    float* A_off    = ws + 15552 + 36864;        // 27*63504 floats

    prep_kernel<<<144, 256, 0, stream>>>(w_off, weight, w_off_t, w_t);

    int waves1 = (Npix + 63) / 64;               // 993
    offconv_kernel<<<(waves1 + 3) / 4, 256, 0, stream>>>(x, w_off_t, b_off, A_off);

    int waves2 = waves1 * 2;                     // 1986
    mdconv_kernel<<<(waves2 + 3) / 4, 256, 0, stream>>>(x, A_off, w_t, bias,
                                                        (float*)d_out);
}

// Round 2
// 169.223 us; speedup vs baseline: 2.7845x; 2.7845x over previous
//
#include <hip/hip_runtime.h>
#include <math.h>

namespace {
constexpr int Bn = 4, Cin = 64, Cout = 64, Hh = 128, Ww = 128, Ho = 126, Wo = 126;
constexpr int Npix = Bn * Ho * Wo;          // 63504
constexpr int HW = Hh * Ww;                 // 16384
constexpr int PixPerImg = Ho * Wo;          // 15876
constexpr int PixWaves = (Npix + 63) / 64;  // 993
}

// ---------------------------------------------------------------------------
// prep: transpose weights for wave-uniform (scalar) reads in hot loops.
//   w_off_t[cin*243 + k*27 + o]  = w_off[o,cin,kh,kw]     (15552 floats)
//   w_t[(k*64+cin)*64 + cout]    = weight[cout,cin,kh,kw] (36864 floats)
// ---------------------------------------------------------------------------
__global__ __launch_bounds__(256) void prep_kernel(
    const float* __restrict__ w_off, const float* __restrict__ weight,
    float* __restrict__ w_off_t, float* __restrict__ w_t)
{
    int i = blockIdx.x * 256 + threadIdx.x;
    if (i < 27 * 64 * 9) {
        int o = i % 27, t = i / 27, k = t % 9, cin = t / 9;
        w_off_t[i] = w_off[o * (64 * 9) + cin * 9 + k];
    }
    if (i < 64 * 64 * 9) {
        int cout = i % 64, t = i / 64, cin = t % 64, k = t / 64;
        w_t[i] = weight[cout * (64 * 9) + cin * 9 + k];
    }
}

// ---------------------------------------------------------------------------
// offset conv (3x3 VALID, 64->27), RAW output (no bias/sigmoid here).
// o-dim split into 3 groups of 9 -> 3x the waves of round 1.
// A_conv[o][Npix] = conv result for channel o.
// ---------------------------------------------------------------------------
__global__ __launch_bounds__(256) void offconv_kernel(
    const float* __restrict__ x, const float* __restrict__ w_off_t,
    float* __restrict__ A_conv)
{
    int wid  = __builtin_amdgcn_readfirstlane((int)(threadIdx.x >> 6));
    int lane = (int)(threadIdx.x & 63);
    int gw = blockIdx.x * 4 + wid;          // 0 .. 2979
    int g  = gw % 3;                        // o-group (wave-uniform)
    int pw = gw / 3;
    int p  = pw * 64 + lane;
    bool active = p < Npix;
    int pc = active ? p : (Npix - 1);
    int b  = pc / PixPerImg;
    int r  = pc - b * PixPerImg;
    int ho = r / Wo;
    int wo = r - ho * Wo;

    float acc[9];
#pragma unroll
    for (int j = 0; j < 9; ++j) acc[j] = 0.f;

    const float* xp = x + b * (Cin * HW) + ho * Ww + wo;
    const float* wbase = w_off_t + 9 * g;
    for (int cin = 0; cin < Cin; ++cin) {
        float xv[9];
#pragma unroll
        for (int kh = 0; kh < 3; ++kh)
#pragma unroll
            for (int kw = 0; kw < 3; ++kw)
                xv[kh * 3 + kw] = xp[cin * HW + kh * Ww + kw];
        const float* wt = wbase + cin * 243;
#pragma unroll
        for (int k = 0; k < 9; ++k) {
            float xk = xv[k];
#pragma unroll
            for (int j = 0; j < 9; ++j)
                acc[j] = fmaf(xk, wt[k * 27 + j], acc[j]);
        }
    }
    if (!active) return;
#pragma unroll
    for (int j = 0; j < 9; ++j)
        A_conv[(9 * g + j) * Npix + p] = acc[j];
}

// ---------------------------------------------------------------------------
// fused sample + contraction. Block = 64 pixels, 4 waves.
// Per k-chunk: wave w bilinear-samples cins [16w,16w+16) into LDS
// [64 cin][64 px] (double-buffered), then all waves contract from LDS
// (lane = pixel, 16 couts per wave, scalar weight stream).
// ---------------------------------------------------------------------------
__global__ __launch_bounds__(256) void fused_kernel(
    const float* __restrict__ x, const float* __restrict__ A_conv,
    const float* __restrict__ b_off, const float* __restrict__ w_t,
    const float* __restrict__ bias, float* __restrict__ out)
{
    __shared__ float lds[2][64][64];   // 32 KB

    int wid  = __builtin_amdgcn_readfirstlane((int)(threadIdx.x >> 6));
    int lane = (int)(threadIdx.x & 63);
    int p  = blockIdx.x * 64 + lane;
    bool active = p < Npix;
    int pc = active ? p : (Npix - 1);
    int b  = pc / PixPerImg;
    int r  = pc - b * PixPerImg;
    int ho = r / Wo;
    int wo = r - ho * Wo;

    const float* xb = x + b * (Cin * HW);

    float acc[16];
#pragma unroll
    for (int c = 0; c < 16; ++c) acc[c] = 0.f;

    // sample chunk k (cins [16*wid,16*wid+16)) into lds[buf]
    auto SAMPLE = [&](int k, int buf) {
        float oy = A_conv[(2 * k) * Npix + pc];
        float ox = A_conv[(2 * k + 1) * Npix + pc];
        float mv = A_conv[(18 + k) * Npix + pc] + b_off[18 + k];
        float ys = (float)(ho + k / 3) + oy + b_off[2 * k];
        float xs = (float)(wo + k % 3) + ox + b_off[2 * k + 1];
        float m  = 1.0f / (1.0f + expf(-mv));
        float y0f = floorf(ys), x0f = floorf(xs);
        float wy = ys - y0f, wx = xs - x0f;
        int y0 = (int)y0f, x0 = (int)x0f;
        float vy0 = (y0 >= 0  && y0 < Hh)     ? 1.f : 0.f;
        float vy1 = (y0 >= -1 && y0 < Hh - 1) ? 1.f : 0.f;
        float vx0 = (x0 >= 0  && x0 < Ww)     ? 1.f : 0.f;
        float vx1 = (x0 >= -1 && x0 < Ww - 1) ? 1.f : 0.f;
        int y0c = min(max(y0, 0), Hh - 1);
        int y1c = min(max(y0 + 1, 0), Hh - 1);
        int x0c = min(max(x0, 0), Ww - 1);
        int x1c = min(max(x0 + 1, 0), Ww - 1);
        float w00 = (1.f - wy) * (1.f - wx) * m * vy0 * vx0;
        float w01 = (1.f - wy) * wx         * m * vy0 * vx1;
        float w10 = wy         * (1.f - wx) * m * vy1 * vx0;
        float w11 = wy         * wx         * m * vy1 * vx1;
        int a00 = y0c * Ww + x0c, a01 = y0c * Ww + x1c;
        int a10 = y1c * Ww + x0c, a11 = y1c * Ww + x1c;
#pragma unroll 4
        for (int i = 0; i < 16; ++i) {
            int cin = wid * 16 + i;
            const float* xc = xb + cin * HW;
            float v00 = xc[a00], v01 = xc[a01], v10 = xc[a10], v11 = xc[a11];
            float s = w00 * v00 + w01 * v01;
            s = fmaf(w10, v10, s);
            s = fmaf(w11, v11, s);
            lds[buf][cin][lane] = s;
        }
    };

    SAMPLE(0, 0);
    __syncthreads();

    for (int k = 0; k < 9; ++k) {
        int cur = k & 1;
        if (k < 8) SAMPLE(k + 1, cur ^ 1);   // prefetch next chunk
        const float* wk = w_t + k * (64 * 64) + wid * 16;
#pragma unroll 8
        for (int cin = 0; cin < 64; ++cin) {
            float a = lds[cur][cin][lane];
            const float* wr = wk + cin * 64;
#pragma unroll
            for (int co = 0; co < 16; ++co)
                acc[co] = fmaf(a, wr[co], acc[co]);
        }
        __syncthreads();
    }

    if (!active) return;
    const int cbase = wid * 16;
#pragma unroll
    for (int co = 0; co < 16; ++co) {
        float v = acc[co] + bias[cbase + co];
        out[((b * Cout + cbase + co) * Ho + ho) * Wo + wo] = fmaxf(v, 0.f);
    }
}

extern "C" void kernel_launch(void* const* d_in, const int* in_sizes, int n_in,
                              void* d_out, int out_size, void* d_ws, size_t ws_size,
                              hipStream_t stream)
{
    const float* x      = (const float*)d_in[0];
    const float* w_off  = (const float*)d_in[1];
    const float* b_off  = (const float*)d_in[2];
    const float* weight = (const float*)d_in[3];
    const float* bias   = (const float*)d_in[4];

    float* ws      = (float*)d_ws;
    float* w_off_t = ws;                     // 15552 floats
    float* w_t     = ws + 15552;             // 36864 floats
    float* A_conv  = ws + 15552 + 36864;     // 27*63504 floats

    prep_kernel<<<144, 256, 0, stream>>>(w_off, weight, w_off_t, w_t);

    int waves1 = PixWaves * 3;               // 2979
    offconv_kernel<<<(waves1 + 3) / 4, 256, 0, stream>>>(x, w_off_t, A_conv);

    fused_kernel<<<PixWaves, 256, 0, stream>>>(x, A_conv, b_off, w_t, bias,
                                               (float*)d_out);
}

// Round 6
// 151.096 us; speedup vs baseline: 3.1185x; 1.1200x over previous
//
#include <hip/hip_runtime.h>
#include <hip/hip_bf16.h>
#include <math.h>

namespace {
constexpr int Bn = 4, Cin = 64, Cout = 64, Hh = 128, Ww = 128, Ho = 126, Wo = 126;
constexpr int Npix = Bn * Ho * Wo;          // 63504
constexpr int HW = Hh * Ww;                 // 16384
constexpr int PixPerImg = Ho * Wo;          // 15876
constexpr int NWG = (Npix + 63) / 64;       // 993 blocks (64 px each)
}

typedef __attribute__((ext_vector_type(8))) short bf16x8;
typedef __attribute__((ext_vector_type(4))) float f32x4;

__device__ __forceinline__ unsigned short f2bf(float f) {
    __hip_bfloat16 h = __float2bfloat16(f);
    return __builtin_bit_cast(unsigned short, h);
}
__device__ __forceinline__ float bf2f(unsigned short u) {
    unsigned int v = (unsigned int)u << 16;
    return __builtin_bit_cast(float, v);
}
__device__ __forceinline__ void split2(float s0, float s1,
                                       unsigned int& hi_pk, unsigned int& lo_pk) {
    unsigned short h0 = f2bf(s0), h1 = f2bf(s1);
    unsigned short l0 = f2bf(s0 - bf2f(h0)), l1 = f2bf(s1 - bf2f(h1));
    hi_pk = (unsigned int)h0 | ((unsigned int)h1 << 16);
    lo_pk = (unsigned int)l0 | ((unsigned int)l1 << 16);
}
__device__ __forceinline__ bf16x8 mk8(unsigned int u0, unsigned int u1,
                                      unsigned int u2, unsigned int u3) {
    union { unsigned int u[4]; bf16x8 v; } x;
    x.u[0] = u0; x.u[1] = u1; x.u[2] = u2; x.u[3] = u3;
    return x.v;
}
// bijective XCD swizzle (m204): contiguous chunk of blocks per XCD
__device__ __forceinline__ int swz_block(int orig, int nwg) {
    int q = nwg >> 3, r = nwg & 7;
    int xcd = orig & 7, idx = orig >> 3;
    return (xcd < r ? xcd * (q + 1) : r * (q + 1) + (xcd - r) * q) + idx;
}

// ---------------------------------------------------------------------------
// prep:
//  w_off_t[cin*243 + k*27 + o] = w_off[o,cin,kh,kw]   (15552 f32, VALU offconv)
//  wA_*[(((k*4+w)*2+h)*64 + l)*8 + j]: main-conv hi/lo bf16 A-fragments,
//        cout=16w+(l&15), cin=32h+8*(l>>4)+j          (36864 bf16 each)
// ---------------------------------------------------------------------------
__global__ __launch_bounds__(256) void prep_kernel(
    const float* __restrict__ w_off, const float* __restrict__ weight,
    float* __restrict__ w_off_t,
    unsigned short* __restrict__ wA_hi, unsigned short* __restrict__ wA_lo)
{
    int i = blockIdx.x * 256 + threadIdx.x;
    if (i < 27 * 64 * 9) {
        int o = i % 27, t = i / 27, k = t % 9, cin = t / 9;
        w_off_t[i] = w_off[o * (64 * 9) + cin * 9 + k];
    }
    if (i < 36864) {
        int j = i % 8;  int t = i / 8;
        int l = t % 64; t /= 64;
        int h = t % 2;  t /= 2;
        int w = t % 4;  int k = t / 4;
        int cout = 16 * w + (l & 15);
        int cin  = 32 * h + 8 * (l >> 4) + j;
        float v = weight[cout * 576 + cin * 9 + k];
        unsigned short hi = f2bf(v);
        wA_hi[i] = hi;
        wA_lo[i] = f2bf(v - bf2f(hi));
    }
}

// ---------------------------------------------------------------------------
// offset conv (3x3 VALID, 64->27), fp32 VALU — round-2 proven version.
// ---------------------------------------------------------------------------
__global__ __launch_bounds__(256) void offconv_kernel(
    const float* __restrict__ x, const float* __restrict__ w_off_t,
    float* __restrict__ A_conv)
{
    int wid  = __builtin_amdgcn_readfirstlane((int)(threadIdx.x >> 6));
    int lane = (int)(threadIdx.x & 63);
    int gw = blockIdx.x * 4 + wid;          // 0 .. 2979
    int g  = gw % 3;                        // o-group (wave-uniform)
    int pw = gw / 3;
    int p  = pw * 64 + lane;
    bool active = p < Npix;
    int pc = active ? p : (Npix - 1);
    int b  = pc / PixPerImg;
    int r  = pc - b * PixPerImg;
    int ho = r / Wo;
    int wo = r - ho * Wo;

    float acc[9];
#pragma unroll
    for (int j = 0; j < 9; ++j) acc[j] = 0.f;

    const float* xp = x + b * (Cin * HW) + ho * Ww + wo;
    const float* wbase = w_off_t + 9 * g;
    for (int cin = 0; cin < Cin; ++cin) {
        float xv[9];
#pragma unroll
        for (int kh = 0; kh < 3; ++kh)
#pragma unroll
            for (int kw = 0; kw < 3; ++kw)
                xv[kh * 3 + kw] = xp[cin * HW + kh * Ww + kw];
        const float* wt = wbase + cin * 243;
#pragma unroll
        for (int k = 0; k < 9; ++k) {
            float xk = xv[k];
#pragma unroll
            for (int j = 0; j < 9; ++j)
                acc[j] = fmaf(xk, wt[k * 27 + j], acc[j]);
        }
    }
    if (!active) return;
#pragma unroll
    for (int j = 0; j < 9; ++j)
        A_conv[(9 * g + j) * Npix + p] = acc[j];
}

// ---------------------------------------------------------------------------
// fused bilinear sample + main conv via split-bf16 MFMA. Block = 64 px, 4 waves.
// LDS layout (NO swizzle, NO vector reinterpret): [buf][plane hi/lo][cp][px]
// where cp = cin>>1, each uint = packed bf16 pair (cin even, cin odd).
// Writer: lane = px, 8 scalar uint stores per plane (bank=lane%32, 2-way, free).
// Reader: B-fragment = 4 scalar uint loads per fragment, assembled in-reg.
// ---------------------------------------------------------------------------
__global__ __launch_bounds__(256, 4) void fused_mfma(
    const float* __restrict__ x, const float* __restrict__ A_conv,
    const float* __restrict__ b_off, const unsigned short* __restrict__ wA_hi,
    const unsigned short* __restrict__ wA_lo, const float* __restrict__ bias,
    float* __restrict__ out)
{
    __shared__ unsigned int lds[2][2][32 * 64];   // 32 KB

    int wg   = swz_block(blockIdx.x, NWG);
    int wid  = __builtin_amdgcn_readfirstlane((int)(threadIdx.x >> 6));
    int lane = (int)(threadIdx.x & 63);
    int p  = wg * 64 + lane;
    int pc = p < Npix ? p : (Npix - 1);
    int b  = pc / PixPerImg;
    int r  = pc - b * PixPerImg;
    int ho = r / Wo;
    int wo = r - ho * Wo;

    const float* xb = x + b * (Cin * HW);

    auto SAMPLE = [&](int k, int buf) {
        float oy = A_conv[(2 * k) * Npix + pc];
        float ox = A_conv[(2 * k + 1) * Npix + pc];
        float mv = A_conv[(18 + k) * Npix + pc] + b_off[18 + k];
        float ys = (float)(ho + k / 3) + oy + b_off[2 * k];
        float xs = (float)(wo + k % 3) + ox + b_off[2 * k + 1];
        float m  = 1.0f / (1.0f + expf(-mv));
        float y0f = floorf(ys), x0f = floorf(xs);
        float wy = ys - y0f, wx = xs - x0f;
        int y0 = (int)y0f, x0 = (int)x0f;
        float vy0 = (y0 >= 0  && y0 < Hh)     ? 1.f : 0.f;
        float vy1 = (y0 >= -1 && y0 < Hh - 1) ? 1.f : 0.f;
        float vx0 = (x0 >= 0  && x0 < Ww)     ? 1.f : 0.f;
        float vx1 = (x0 >= -1 && x0 < Ww - 1) ? 1.f : 0.f;
        int y0c = min(max(y0, 0), Hh - 1);
        int y1c = min(max(y0 + 1, 0), Hh - 1);
        int x0c = min(max(x0, 0), Ww - 1);
        int x1c = min(max(x0 + 1, 0), Ww - 1);
        float w00 = (1.f - wy) * (1.f - wx) * m * vy0 * vx0;
        float w01 = (1.f - wy) * wx         * m * vy0 * vx1;
        float w10 = wy         * (1.f - wx) * m * vy1 * vx0;
        float w11 = wy         * wx         * m * vy1 * vx1;
        int a00 = y0c * Ww + x0c, a01 = y0c * Ww + x1c;
        int a10 = y1c * Ww + x0c, a11 = y1c * Ww + x1c;
#pragma unroll
        for (int pr = 0; pr < 8; ++pr) {
            const float* xc0 = xb + (wid * 16 + 2 * pr) * HW;
            const float* xc1 = xc0 + HW;
            float s0 = w00 * xc0[a00] + w01 * xc0[a01];
            s0 = fmaf(w10, xc0[a10], s0);
            s0 = fmaf(w11, xc0[a11], s0);
            float s1 = w00 * xc1[a00] + w01 * xc1[a01];
            s1 = fmaf(w10, xc1[a10], s1);
            s1 = fmaf(w11, xc1[a11], s1);
            unsigned int hp, lp;
            split2(s0, s1, hp, lp);
            // cin pair (16*wid + 2*pr, +1)  ->  cp row = 8*wid + pr, col = lane
            lds[buf][0][(8 * wid + pr) * 64 + lane] = hp;
            lds[buf][1][(8 * wid + pr) * 64 + lane] = lp;
        }
    };

    f32x4 acc[4];
#pragma unroll
    for (int t = 0; t < 4; ++t) acc[t] = {0.f, 0.f, 0.f, 0.f};

    SAMPLE(0, 0);
    __syncthreads();

    for (int k = 0; k < 9; ++k) {
        int cur = k & 1;
        if (k < 8) SAMPLE(k + 1, cur ^ 1);
        const bf16x8* waH = reinterpret_cast<const bf16x8*>(
            wA_hi + ((k * 4 + wid) * 2) * 512 + lane * 8);
        const bf16x8* waL = reinterpret_cast<const bf16x8*>(
            wA_lo + ((k * 4 + wid) * 2) * 512 + lane * 8);
        bf16x8 a0h = waH[0], a1h = waH[64];
        bf16x8 a0l = waL[0], a1l = waL[64];
        const unsigned int* Lh = &lds[cur][0][0];
        const unsigned int* Ll = &lds[cur][1][0];
        int g4 = (lane >> 4) * 4;
#pragma unroll
        for (int t = 0; t < 4; ++t) {
            int colp = 16 * t + (lane & 15);
            // b0: cins 8g..8g+7 (cp rows g4..g4+3); b1: cins 32+8g.. (cp rows 16+g4..)
            bf16x8 b0h = mk8(Lh[(g4 + 0) * 64 + colp], Lh[(g4 + 1) * 64 + colp],
                             Lh[(g4 + 2) * 64 + colp], Lh[(g4 + 3) * 64 + colp]);
            bf16x8 b1h = mk8(Lh[(16 + g4 + 0) * 64 + colp], Lh[(16 + g4 + 1) * 64 + colp],
                             Lh[(16 + g4 + 2) * 64 + colp], Lh[(16 + g4 + 3) * 64 + colp]);
            bf16x8 b0l = mk8(Ll[(g4 + 0) * 64 + colp], Ll[(g4 + 1) * 64 + colp],
                             Ll[(g4 + 2) * 64 + colp], Ll[(g4 + 3) * 64 + colp]);
            bf16x8 b1l = mk8(Ll[(16 + g4 + 0) * 64 + colp], Ll[(16 + g4 + 1) * 64 + colp],
                             Ll[(16 + g4 + 2) * 64 + colp], Ll[(16 + g4 + 3) * 64 + colp]);
            acc[t] = __builtin_amdgcn_mfma_f32_16x16x32_bf16(a0h, b0h, acc[t], 0, 0, 0);
            acc[t] = __builtin_amdgcn_mfma_f32_16x16x32_bf16(a0l, b0h, acc[t], 0, 0, 0);
            acc[t] = __builtin_amdgcn_mfma_f32_16x16x32_bf16(a0h, b0l, acc[t], 0, 0, 0);
            acc[t] = __builtin_amdgcn_mfma_f32_16x16x32_bf16(a1h, b1h, acc[t], 0, 0, 0);
            acc[t] = __builtin_amdgcn_mfma_f32_16x16x32_bf16(a1l, b1h, acc[t], 0, 0, 0);
            acc[t] = __builtin_amdgcn_mfma_f32_16x16x32_bf16(a1h, b1l, acc[t], 0, 0, 0);
        }
        __syncthreads();
    }

#pragma unroll
    for (int t = 0; t < 4; ++t) {
        int p2 = wg * 64 + 16 * t + (lane & 15);
        if (p2 >= Npix) continue;
        int b2 = p2 / PixPerImg;
        int r2 = p2 - b2 * PixPerImg;
        int ho2 = r2 / Wo;
        int wo2 = r2 - ho2 * Wo;
#pragma unroll
        for (int rg = 0; rg < 4; ++rg) {
            int cout = 16 * wid + 4 * (lane >> 4) + rg;
            float v = acc[t][rg] + bias[cout];
            out[((b2 * Cout + cout) * Ho + ho2) * Wo + wo2] = fmaxf(v, 0.f);
        }
    }
}

extern "C" void kernel_launch(void* const* d_in, const int* in_sizes, int n_in,
                              void* d_out, int out_size, void* d_ws, size_t ws_size,
                              hipStream_t stream)
{
    const float* x      = (const float*)d_in[0];
    const float* w_off  = (const float*)d_in[1];
    const float* b_off  = (const float*)d_in[2];
    const float* weight = (const float*)d_in[3];
    const float* bias   = (const float*)d_in[4];

    float* A_conv  = (float*)d_ws;                         // 27*Npix f32
    float* w_off_t = A_conv + 27 * Npix;                   // 15552 f32
    unsigned short* wA_hi = (unsigned short*)(w_off_t + 15552);  // 36864 bf16
    unsigned short* wA_lo = wA_hi + 36864;                 // 36864 bf16

    prep_kernel<<<144, 256, 0, stream>>>(w_off, weight, w_off_t, wA_hi, wA_lo);

    int waves1 = NWG * 3;                                  // 2979
    offconv_kernel<<<(waves1 + 3) / 4, 256, 0, stream>>>(x, w_off_t, A_conv);

    fused_mfma<<<NWG, 256, 0, stream>>>(x, A_conv, b_off, wA_hi, wA_lo, bias,
                                        (float*)d_out);
}

// Round 8
// 128.177 us; speedup vs baseline: 3.6761x; 1.1788x over previous
//
#include <hip/hip_runtime.h>
#include <hip/hip_bf16.h>
#include <math.h>

namespace {
constexpr int Bn = 4, Cin = 64, Cout = 64, Hh = 128, Ww = 128, Ho = 126, Wo = 126;
constexpr int Npix = Bn * Ho * Wo;          // 63504
constexpr int HW = Hh * Ww;                 // 16384
constexpr int PixPerImg = Ho * Wo;          // 15876
constexpr int NWG = (Npix + 63) / 64;       // 993 blocks (64 px each)
}

typedef __attribute__((ext_vector_type(8))) short bf16x8;
typedef __attribute__((ext_vector_type(4))) float f32x4;

__device__ __forceinline__ unsigned short f2bf(float f) {
    __hip_bfloat16 h = __float2bfloat16(f);
    return __builtin_bit_cast(unsigned short, h);
}
__device__ __forceinline__ float bf2f(unsigned short u) {
    unsigned int v = (unsigned int)u << 16;
    return __builtin_bit_cast(float, v);
}
__device__ __forceinline__ void split2(float s0, float s1,
                                       unsigned int& hi_pk, unsigned int& lo_pk) {
    unsigned short h0 = f2bf(s0), h1 = f2bf(s1);
    unsigned short l0 = f2bf(s0 - bf2f(h0)), l1 = f2bf(s1 - bf2f(h1));
    hi_pk = (unsigned int)h0 | ((unsigned int)h1 << 16);
    lo_pk = (unsigned int)l0 | ((unsigned int)l1 << 16);
}
__device__ __forceinline__ bf16x8 mk8(unsigned int u0, unsigned int u1,
                                      unsigned int u2, unsigned int u3) {
    union { unsigned int u[4]; bf16x8 v; } x;
    x.u[0] = u0; x.u[1] = u1; x.u[2] = u2; x.u[3] = u3;
    return x.v;
}
// bijective XCD swizzle (m204): contiguous chunk of blocks per XCD
__device__ __forceinline__ int swz_block(int orig, int nwg) {
    int q = nwg >> 3, r = nwg & 7;
    int xcd = orig & 7, idx = orig >> 3;
    return (xcd < r ? xcd * (q + 1) : r * (q + 1) + (xcd - r) * q) + idx;
}

// ---------------------------------------------------------------------------
// prep: hi/lo bf16 A-fragment streams, PROVEN mapping (R6).
//  wA_*  [(((k*4+w)*2+h)*64 + l)*8 + j]: cout=16w+(l&15), cin=32h+8*(l>>4)+j
//  wOff64_*: SAME formula, o=16w+(l&15) zero-padded for o>=27 (64-row pad)
// ---------------------------------------------------------------------------
__global__ __launch_bounds__(256) void prep_kernel(
    const float* __restrict__ w_off, const float* __restrict__ weight,
    unsigned short* __restrict__ wA_hi, unsigned short* __restrict__ wA_lo,
    unsigned short* __restrict__ wOff_hi, unsigned short* __restrict__ wOff_lo)
{
    int i = blockIdx.x * 256 + threadIdx.x;
    if (i < 36864) {
        int j = i % 8;  int t = i / 8;
        int l = t % 64; t /= 64;
        int h = t % 2;  t /= 2;
        int w = t % 4;  int k = t / 4;
        int cout = 16 * w + (l & 15);
        int cin  = 32 * h + 8 * (l >> 4) + j;
        float v = weight[cout * 576 + cin * 9 + k];
        unsigned short hi = f2bf(v);
        wA_hi[i] = hi;
        wA_lo[i] = f2bf(v - bf2f(hi));

        int o = cout;   // same index domain, zero-padded past 27
        float vo = o < 27 ? w_off[o * 576 + cin * 9 + k] : 0.f;
        unsigned short oh = f2bf(vo);
        wOff_hi[i] = oh;
        wOff_lo[i] = f2bf(vo - bf2f(oh));
    }
}

// ---------------------------------------------------------------------------
// offset conv (3x3 VALID, 64->27) — LITERAL CLONE of the R6-proven fused_mfma:
// identical scalar LDS [buf][hi/lo][cp][px], identical mk8 fragment reads,
// identical MFMA block and epilogue map. Diffs ONLY: plain 3x3 loads instead
// of bilinear sampling; output -> A_conv with o<27 guard; waves 2,3 stage-only
// (their couts are zero padding).
// ---------------------------------------------------------------------------
__global__ __launch_bounds__(256, 4) void offconv_mfma(
    const float* __restrict__ x, const unsigned short* __restrict__ wOff_hi,
    const unsigned short* __restrict__ wOff_lo, float* __restrict__ A_conv)
{
    __shared__ unsigned int lds[2][2][32 * 64];   // 32 KB

    int wg   = swz_block(blockIdx.x, NWG);
    int wid  = __builtin_amdgcn_readfirstlane((int)(threadIdx.x >> 6));
    int lane = (int)(threadIdx.x & 63);
    int p  = wg * 64 + lane;
    int pc = p < Npix ? p : (Npix - 1);
    int b  = pc / PixPerImg;
    int r  = pc - b * PixPerImg;
    int ho = r / Wo;
    int wo = r - ho * Wo;

    const float* xb = x + b * (Cin * HW) + ho * Ww + wo;

    auto STAGE = [&](int k, int buf) {
        int kh = k / 3, kw = k - 3 * kh;
        const float* base = xb + kh * Ww + kw;
#pragma unroll
        for (int pr = 0; pr < 8; ++pr) {
            float s0 = base[(wid * 16 + 2 * pr) * HW];
            float s1 = base[(wid * 16 + 2 * pr + 1) * HW];
            unsigned int hp, lp;
            split2(s0, s1, hp, lp);
            lds[buf][0][(8 * wid + pr) * 64 + lane] = hp;
            lds[buf][1][(8 * wid + pr) * 64 + lane] = lp;
        }
    };

    f32x4 acc[4];
#pragma unroll
    for (int t = 0; t < 4; ++t) acc[t] = {0.f, 0.f, 0.f, 0.f};

    STAGE(0, 0);
    __syncthreads();

    for (int k = 0; k < 9; ++k) {
        int cur = k & 1;
        if (k < 8) STAGE(k + 1, cur ^ 1);
        if (wid < 2) {
            const bf16x8* waH = reinterpret_cast<const bf16x8*>(
                wOff_hi + ((k * 4 + wid) * 2) * 512 + lane * 8);
            const bf16x8* waL = reinterpret_cast<const bf16x8*>(
                wOff_lo + ((k * 4 + wid) * 2) * 512 + lane * 8);
            bf16x8 a0h = waH[0], a1h = waH[64];
            bf16x8 a0l = waL[0], a1l = waL[64];
            const unsigned int* Lh = &lds[cur][0][0];
            const unsigned int* Ll = &lds[cur][1][0];
            int g4 = (lane >> 4) * 4;
#pragma unroll
            for (int t = 0; t < 4; ++t) {
                int colp = 16 * t + (lane & 15);
                bf16x8 b0h = mk8(Lh[(g4 + 0) * 64 + colp], Lh[(g4 + 1) * 64 + colp],
                                 Lh[(g4 + 2) * 64 + colp], Lh[(g4 + 3) * 64 + colp]);
                bf16x8 b1h = mk8(Lh[(16 + g4 + 0) * 64 + colp], Lh[(16 + g4 + 1) * 64 + colp],
                                 Lh[(16 + g4 + 2) * 64 + colp], Lh[(16 + g4 + 3) * 64 + colp]);
                bf16x8 b0l = mk8(Ll[(g4 + 0) * 64 + colp], Ll[(g4 + 1) * 64 + colp],
                                 Ll[(g4 + 2) * 64 + colp], Ll[(g4 + 3) * 64 + colp]);
                bf16x8 b1l = mk8(Ll[(16 + g4 + 0) * 64 + colp], Ll[(16 + g4 + 1) * 64 + colp],
                                 Ll[(16 + g4 + 2) * 64 + colp], Ll[(16 + g4 + 3) * 64 + colp]);
                acc[t] = __builtin_amdgcn_mfma_f32_16x16x32_bf16(a0h, b0h, acc[t], 0, 0, 0);
                acc[t] = __builtin_amdgcn_mfma_f32_16x16x32_bf16(a0l, b0h, acc[t], 0, 0, 0);
                acc[t] = __builtin_amdgcn_mfma_f32_16x16x32_bf16(a0h, b0l, acc[t], 0, 0, 0);
                acc[t] = __builtin_amdgcn_mfma_f32_16x16x32_bf16(a1h, b1h, acc[t], 0, 0, 0);
                acc[t] = __builtin_amdgcn_mfma_f32_16x16x32_bf16(a1l, b1h, acc[t], 0, 0, 0);
                acc[t] = __builtin_amdgcn_mfma_f32_16x16x32_bf16(a1h, b1l, acc[t], 0, 0, 0);
            }
        }
        __syncthreads();
    }

    if (wid < 2) {
#pragma unroll
        for (int t = 0; t < 4; ++t) {
            int p2 = wg * 64 + 16 * t + (lane & 15);
            if (p2 >= Npix) continue;
#pragma unroll
            for (int rg = 0; rg < 4; ++rg) {
                int o = 16 * wid + 4 * (lane >> 4) + rg;
                if (o < 27) A_conv[o * Npix + p2] = acc[t][rg];
            }
        }
    }
}

// ---------------------------------------------------------------------------
// fused bilinear sample + main conv via split-bf16 MFMA — BYTE-IDENTICAL to
// the R6 passing version (all-scalar LDS, [cp][px] layout, mk8 reads).
// ---------------------------------------------------------------------------
__global__ __launch_bounds__(256, 4) void fused_mfma(
    const float* __restrict__ x, const float* __restrict__ A_conv,
    const float* __restrict__ b_off, const unsigned short* __restrict__ wA_hi,
    const unsigned short* __restrict__ wA_lo, const float* __restrict__ bias,
    float* __restrict__ out)
{
    __shared__ unsigned int lds[2][2][32 * 64];   // 32 KB

    int wg   = swz_block(blockIdx.x, NWG);
    int wid  = __builtin_amdgcn_readfirstlane((int)(threadIdx.x >> 6));
    int lane = (int)(threadIdx.x & 63);
    int p  = wg * 64 + lane;
    int pc = p < Npix ? p : (Npix - 1);
    int b  = pc / PixPerImg;
    int r  = pc - b * PixPerImg;
    int ho = r / Wo;
    int wo = r - ho * Wo;

    const float* xb = x + b * (Cin * HW);

    auto SAMPLE = [&](int k, int buf) {
        float oy = A_conv[(2 * k) * Npix + pc];
        float ox = A_conv[(2 * k + 1) * Npix + pc];
        float mv = A_conv[(18 + k) * Npix + pc] + b_off[18 + k];
        float ys = (float)(ho + k / 3) + oy + b_off[2 * k];
        float xs = (float)(wo + k % 3) + ox + b_off[2 * k + 1];
        float m  = 1.0f / (1.0f + expf(-mv));
        float y0f = floorf(ys), x0f = floorf(xs);
        float wy = ys - y0f, wx = xs - x0f;
        int y0 = (int)y0f, x0 = (int)x0f;
        float vy0 = (y0 >= 0  && y0 < Hh)     ? 1.f : 0.f;
        float vy1 = (y0 >= -1 && y0 < Hh - 1) ? 1.f : 0.f;
        float vx0 = (x0 >= 0  && x0 < Ww)     ? 1.f : 0.f;
        float vx1 = (x0 >= -1 && x0 < Ww - 1) ? 1.f : 0.f;
        int y0c = min(max(y0, 0), Hh - 1);
        int y1c = min(max(y0 + 1, 0), Hh - 1);
        int x0c = min(max(x0, 0), Ww - 1);
        int x1c = min(max(x0 + 1, 0), Ww - 1);
        float w00 = (1.f - wy) * (1.f - wx) * m * vy0 * vx0;
        float w01 = (1.f - wy) * wx         * m * vy0 * vx1;
        float w10 = wy         * (1.f - wx) * m * vy1 * vx0;
        float w11 = wy         * wx         * m * vy1 * vx1;
        int a00 = y0c * Ww + x0c, a01 = y0c * Ww + x1c;
        int a10 = y1c * Ww + x0c, a11 = y1c * Ww + x1c;
#pragma unroll
        for (int pr = 0; pr < 8; ++pr) {
            const float* xc0 = xb + (wid * 16 + 2 * pr) * HW;
            const float* xc1 = xc0 + HW;
            float s0 = w00 * xc0[a00] + w01 * xc0[a01];
            s0 = fmaf(w10, xc0[a10], s0);
            s0 = fmaf(w11, xc0[a11], s0);
            float s1 = w00 * xc1[a00] + w01 * xc1[a01];
            s1 = fmaf(w10, xc1[a10], s1);
            s1 = fmaf(w11, xc1[a11], s1);
            unsigned int hp, lp;
            split2(s0, s1, hp, lp);
            lds[buf][0][(8 * wid + pr) * 64 + lane] = hp;
            lds[buf][1][(8 * wid + pr) * 64 + lane] = lp;
        }
    };

    f32x4 acc[4];
#pragma unroll
    for (int t = 0; t < 4; ++t) acc[t] = {0.f, 0.f, 0.f, 0.f};

    SAMPLE(0, 0);
    __syncthreads();

    for (int k = 0; k < 9; ++k) {
        int cur = k & 1;
        if (k < 8) SAMPLE(k + 1, cur ^ 1);
        const bf16x8* waH = reinterpret_cast<const bf16x8*>(
            wA_hi + ((k * 4 + wid) * 2) * 512 + lane * 8);
        const bf16x8* waL = reinterpret_cast<const bf16x8*>(
            wA_lo + ((k * 4 + wid) * 2) * 512 + lane * 8);
        bf16x8 a0h = waH[0], a1h = waH[64];
        bf16x8 a0l = waL[0], a1l = waL[64];
        const unsigned int* Lh = &lds[cur][0][0];
        const unsigned int* Ll = &lds[cur][1][0];
        int g4 = (lane >> 4) * 4;
#pragma unroll
        for (int t = 0; t < 4; ++t) {
            int colp = 16 * t + (lane & 15);
            bf16x8 b0h = mk8(Lh[(g4 + 0) * 64 + colp], Lh[(g4 + 1) * 64 + colp],
                             Lh[(g4 + 2) * 64 + colp], Lh[(g4 + 3) * 64 + colp]);
            bf16x8 b1h = mk8(Lh[(16 + g4 + 0) * 64 + colp], Lh[(16 + g4 + 1) * 64 + colp],
                             Lh[(16 + g4 + 2) * 64 + colp], Lh[(16 + g4 + 3) * 64 + colp]);
            bf16x8 b0l = mk8(Ll[(g4 + 0) * 64 + colp], Ll[(g4 + 1) * 64 + colp],
                             Ll[(g4 + 2) * 64 + colp], Ll[(g4 + 3) * 64 + colp]);
            bf16x8 b1l = mk8(Ll[(16 + g4 + 0) * 64 + colp], Ll[(16 + g4 + 1) * 64 + colp],
                             Ll[(16 + g4 + 2) * 64 + colp], Ll[(16 + g4 + 3) * 64 + colp]);
            acc[t] = __builtin_amdgcn_mfma_f32_16x16x32_bf16(a0h, b0h, acc[t], 0, 0, 0);
            acc[t] = __builtin_amdgcn_mfma_f32_16x16x32_bf16(a0l, b0h, acc[t], 0, 0, 0);
            acc[t] = __builtin_amdgcn_mfma_f32_16x16x32_bf16(a0h, b0l, acc[t], 0, 0, 0);
            acc[t] = __builtin_amdgcn_mfma_f32_16x16x32_bf16(a1h, b1h, acc[t], 0, 0, 0);
            acc[t] = __builtin_amdgcn_mfma_f32_16x16x32_bf16(a1l, b1h, acc[t], 0, 0, 0);
            acc[t] = __builtin_amdgcn_mfma_f32_16x16x32_bf16(a1h, b1l, acc[t], 0, 0, 0);
        }
        __syncthreads();
    }

#pragma unroll
    for (int t = 0; t < 4; ++t) {
        int p2 = wg * 64 + 16 * t + (lane & 15);
        if (p2 >= Npix) continue;
        int b2 = p2 / PixPerImg;
        int r2 = p2 - b2 * PixPerImg;
        int ho2 = r2 / Wo;
        int wo2 = r2 - ho2 * Wo;
#pragma unroll
        for (int rg = 0; rg < 4; ++rg) {
            int cout = 16 * wid + 4 * (lane >> 4) + rg;
            float v = acc[t][rg] + bias[cout];
            out[((b2 * Cout + cout) * Ho + ho2) * Wo + wo2] = fmaxf(v, 0.f);
        }
    }
}

extern "C" void kernel_launch(void* const* d_in, const int* in_sizes, int n_in,
                              void* d_out, int out_size, void* d_ws, size_t ws_size,
                              hipStream_t stream)
{
    const float* x      = (const float*)d_in[0];
    const float* w_off  = (const float*)d_in[1];
    const float* b_off  = (const float*)d_in[2];
    const float* weight = (const float*)d_in[3];
    const float* bias   = (const float*)d_in[4];

    float* A_conv = (float*)d_ws;                               // 27*Npix f32
    unsigned short* wA_hi   = (unsigned short*)(A_conv + 27 * Npix);
    unsigned short* wA_lo   = wA_hi + 36864;
    unsigned short* wOff_hi = wA_lo + 36864;
    unsigned short* wOff_lo = wOff_hi + 36864;

    prep_kernel<<<144, 256, 0, stream>>>(w_off, weight, wA_hi, wA_lo,
                                         wOff_hi, wOff_lo);
    offconv_mfma<<<NWG, 256, 0, stream>>>(x, wOff_hi, wOff_lo, A_conv);
    fused_mfma<<<NWG, 256, 0, stream>>>(x, A_conv, b_off, wA_hi, wA_lo, bias,
                                        (float*)d_out);
}

// Round 9
// 118.799 us; speedup vs baseline: 3.9664x; 1.0789x over previous
//
#include <hip/hip_runtime.h>
#include <hip/hip_bf16.h>
#include <math.h>

namespace {
constexpr int Bn = 4, Cin = 64, Cout = 64, Hh = 128, Ww = 128, Ho = 126, Wo = 126;
constexpr int Npix = Bn * Ho * Wo;          // 63504
constexpr int HW = Hh * Ww;                 // 16384
constexpr int PixPerImg = Ho * Wo;          // 15876
constexpr int NWG = (Npix + 63) / 64;       // 993 blocks (64 px each)
}

typedef __attribute__((ext_vector_type(8))) short bf16x8;
typedef __attribute__((ext_vector_type(4))) float f32x4;

__device__ __forceinline__ unsigned short f2bf(float f) {
    __hip_bfloat16 h = __float2bfloat16(f);
    return __builtin_bit_cast(unsigned short, h);
}
__device__ __forceinline__ float bf2f(unsigned short u) {
    unsigned int v = (unsigned int)u << 16;
    return __builtin_bit_cast(float, v);
}
__device__ __forceinline__ void split2(float s0, float s1,
                                       unsigned int& hi_pk, unsigned int& lo_pk) {
    unsigned short h0 = f2bf(s0), h1 = f2bf(s1);
    unsigned short l0 = f2bf(s0 - bf2f(h0)), l1 = f2bf(s1 - bf2f(h1));
    hi_pk = (unsigned int)h0 | ((unsigned int)h1 << 16);
    lo_pk = (unsigned int)l0 | ((unsigned int)l1 << 16);
}
__device__ __forceinline__ bf16x8 mk8(unsigned int u0, unsigned int u1,
                                      unsigned int u2, unsigned int u3) {
    union { unsigned int u[4]; bf16x8 v; } x;
    x.u[0] = u0; x.u[1] = u1; x.u[2] = u2; x.u[3] = u3;
    return x.v;
}
// bijective XCD swizzle (m204): contiguous chunk of blocks per XCD
__device__ __forceinline__ int swz_block(int orig, int nwg) {
    int q = nwg >> 3, r = nwg & 7;
    int xcd = orig & 7, idx = orig >> 3;
    return (xcd < r ? xcd * (q + 1) : r * (q + 1) + (xcd - r) * q) + idx;
}

// ---------------------------------------------------------------------------
// prep: hi/lo bf16 A-fragment streams, PROVEN mapping (R6/R8).
// ---------------------------------------------------------------------------
__global__ __launch_bounds__(256) void prep_kernel(
    const float* __restrict__ w_off, const float* __restrict__ weight,
    unsigned short* __restrict__ wA_hi, unsigned short* __restrict__ wA_lo,
    unsigned short* __restrict__ wOff_hi, unsigned short* __restrict__ wOff_lo)
{
    int i = blockIdx.x * 256 + threadIdx.x;
    if (i < 36864) {
        int j = i % 8;  int t = i / 8;
        int l = t % 64; t /= 64;
        int h = t % 2;  t /= 2;
        int w = t % 4;  int k = t / 4;
        int cout = 16 * w + (l & 15);
        int cin  = 32 * h + 8 * (l >> 4) + j;
        float v = weight[cout * 576 + cin * 9 + k];
        unsigned short hi = f2bf(v);
        wA_hi[i] = hi;
        wA_lo[i] = f2bf(v - bf2f(hi));

        int o = cout;   // same index domain, zero-padded past 27
        float vo = o < 27 ? w_off[o * 576 + cin * 9 + k] : 0.f;
        unsigned short oh = f2bf(vo);
        wOff_hi[i] = oh;
        wOff_lo[i] = f2bf(vo - bf2f(oh));
    }
}

// ---------------------------------------------------------------------------
// NCHW -> NHWC transpose: xT[(b*HW + hw)*64 + c] = x[b][c][hw].
// Tiled via LDS (scalar f32 accesses only), fully coalesced both sides.
// Grid: Bn * (HW/64) = 1024 blocks, 256 threads.
// ---------------------------------------------------------------------------
__global__ __launch_bounds__(256) void transpose_kernel(
    const float* __restrict__ x, float* __restrict__ xT)
{
    __shared__ float t[64][65];
    int blk  = blockIdx.x;
    int b    = blk >> 8;                 // HW/64 = 256 chunks per image
    int hw0  = (blk & 255) * 64;
    int lane = (int)(threadIdx.x & 63);
    int w4   = (int)(threadIdx.x >> 6);  // 0..3

    const float* xb = x + b * (Cin * HW) + hw0;
#pragma unroll
    for (int i = 0; i < 16; ++i) {
        int cin = w4 * 16 + i;
        t[cin][lane] = xb[cin * HW + lane];
    }
    __syncthreads();
    float* dst = xT + (b * HW + hw0) * 64;
#pragma unroll
    for (int i = 0; i < 16; ++i) {
        int px = w4 * 16 + i;
        dst[px * 64 + lane] = t[lane][px];
    }
}

// ---------------------------------------------------------------------------
// offset conv (3x3 VALID, 64->27) via split-bf16 MFMA — R8 proven version,
// unchanged (gathers are naturally coalesced in NCHW).
// ---------------------------------------------------------------------------
__global__ __launch_bounds__(256, 4) void offconv_mfma(
    const float* __restrict__ x, const unsigned short* __restrict__ wOff_hi,
    const unsigned short* __restrict__ wOff_lo, float* __restrict__ A_conv)
{
    __shared__ unsigned int lds[2][2][32 * 64];   // 32 KB

    int wg   = swz_block(blockIdx.x, NWG);
    int wid  = __builtin_amdgcn_readfirstlane((int)(threadIdx.x >> 6));
    int lane = (int)(threadIdx.x & 63);
    int p  = wg * 64 + lane;
    int pc = p < Npix ? p : (Npix - 1);
    int b  = pc / PixPerImg;
    int r  = pc - b * PixPerImg;
    int ho = r / Wo;
    int wo = r - ho * Wo;

    const float* xb = x + b * (Cin * HW) + ho * Ww + wo;

    auto STAGE = [&](int k, int buf) {
        int kh = k / 3, kw = k - 3 * kh;
        const float* base = xb + kh * Ww + kw;
#pragma unroll
        for (int pr = 0; pr < 8; ++pr) {
            float s0 = base[(wid * 16 + 2 * pr) * HW];
            float s1 = base[(wid * 16 + 2 * pr + 1) * HW];
            unsigned int hp, lp;
            split2(s0, s1, hp, lp);
            lds[buf][0][(8 * wid + pr) * 64 + lane] = hp;
            lds[buf][1][(8 * wid + pr) * 64 + lane] = lp;
        }
    };

    f32x4 acc[4];
#pragma unroll
    for (int t = 0; t < 4; ++t) acc[t] = {0.f, 0.f, 0.f, 0.f};

    STAGE(0, 0);
    __syncthreads();

    for (int k = 0; k < 9; ++k) {
        int cur = k & 1;
        if (k < 8) STAGE(k + 1, cur ^ 1);
        if (wid < 2) {
            const bf16x8* waH = reinterpret_cast<const bf16x8*>(
                wOff_hi + ((k * 4 + wid) * 2) * 512 + lane * 8);
            const bf16x8* waL = reinterpret_cast<const bf16x8*>(
                wOff_lo + ((k * 4 + wid) * 2) * 512 + lane * 8);
            bf16x8 a0h = waH[0], a1h = waH[64];
            bf16x8 a0l = waL[0], a1l = waL[64];
            const unsigned int* Lh = &lds[cur][0][0];
            const unsigned int* Ll = &lds[cur][1][0];
            int g4 = (lane >> 4) * 4;
#pragma unroll
            for (int t = 0; t < 4; ++t) {
                int colp = 16 * t + (lane & 15);
                bf16x8 b0h = mk8(Lh[(g4 + 0) * 64 + colp], Lh[(g4 + 1) * 64 + colp],
                                 Lh[(g4 + 2) * 64 + colp], Lh[(g4 + 3) * 64 + colp]);
                bf16x8 b1h = mk8(Lh[(16 + g4 + 0) * 64 + colp], Lh[(16 + g4 + 1) * 64 + colp],
                                 Lh[(16 + g4 + 2) * 64 + colp], Lh[(16 + g4 + 3) * 64 + colp]);
                bf16x8 b0l = mk8(Ll[(g4 + 0) * 64 + colp], Ll[(g4 + 1) * 64 + colp],
                                 Ll[(g4 + 2) * 64 + colp], Ll[(g4 + 3) * 64 + colp]);
                bf16x8 b1l = mk8(Ll[(16 + g4 + 0) * 64 + colp], Ll[(16 + g4 + 1) * 64 + colp],
                                 Ll[(16 + g4 + 2) * 64 + colp], Ll[(16 + g4 + 3) * 64 + colp]);
                acc[t] = __builtin_amdgcn_mfma_f32_16x16x32_bf16(a0h, b0h, acc[t], 0, 0, 0);
                acc[t] = __builtin_amdgcn_mfma_f32_16x16x32_bf16(a0l, b0h, acc[t], 0, 0, 0);
                acc[t] = __builtin_amdgcn_mfma_f32_16x16x32_bf16(a0h, b0l, acc[t], 0, 0, 0);
                acc[t] = __builtin_amdgcn_mfma_f32_16x16x32_bf16(a1h, b1h, acc[t], 0, 0, 0);
                acc[t] = __builtin_amdgcn_mfma_f32_16x16x32_bf16(a1l, b1h, acc[t], 0, 0, 0);
                acc[t] = __builtin_amdgcn_mfma_f32_16x16x32_bf16(a1h, b1l, acc[t], 0, 0, 0);
            }
        }
        __syncthreads();
    }

    if (wid < 2) {
#pragma unroll
        for (int t = 0; t < 4; ++t) {
            int p2 = wg * 64 + 16 * t + (lane & 15);
            if (p2 >= Npix) continue;
#pragma unroll
            for (int rg = 0; rg < 4; ++rg) {
                int o = 16 * wid + 4 * (lane >> 4) + rg;
                if (o < 27) A_conv[o * Npix + p2] = acc[t][rg];
            }
        }
    }
}

// ---------------------------------------------------------------------------
// fused bilinear sample + main conv via split-bf16 MFMA.
// CHANGE vs R8: gathers read NHWC xT — per corner, 16 cins = 4 float4 loads
// (64B aligned). 16 VMEM gathers/lane/k instead of 64. Scalar LDS unchanged.
// ---------------------------------------------------------------------------
__global__ __launch_bounds__(256, 4) void fused_mfma(
    const float* __restrict__ xT, const float* __restrict__ A_conv,
    const float* __restrict__ b_off, const unsigned short* __restrict__ wA_hi,
    const unsigned short* __restrict__ wA_lo, const float* __restrict__ bias,
    float* __restrict__ out)
{
    __shared__ unsigned int lds[2][2][32 * 64];   // 32 KB

    int wg   = swz_block(blockIdx.x, NWG);
    int wid  = __builtin_amdgcn_readfirstlane((int)(threadIdx.x >> 6));
    int lane = (int)(threadIdx.x & 63);
    int p  = wg * 64 + lane;
    int pc = p < Npix ? p : (Npix - 1);
    int b  = pc / PixPerImg;
    int r  = pc - b * PixPerImg;
    int ho = r / Wo;
    int wo = r - ho * Wo;

    const float* xTb = xT + (size_t)b * HW * 64;

    auto SAMPLE = [&](int k, int buf) {
        float oy = A_conv[(2 * k) * Npix + pc];
        float ox = A_conv[(2 * k + 1) * Npix + pc];
        float mv = A_conv[(18 + k) * Npix + pc] + b_off[18 + k];
        float ys = (float)(ho + k / 3) + oy + b_off[2 * k];
        float xs = (float)(wo + k % 3) + ox + b_off[2 * k + 1];
        float m  = 1.0f / (1.0f + expf(-mv));
        float y0f = floorf(ys), x0f = floorf(xs);
        float wy = ys - y0f, wx = xs - x0f;
        int y0 = (int)y0f, x0 = (int)x0f;
        float vy0 = (y0 >= 0  && y0 < Hh)     ? 1.f : 0.f;
        float vy1 = (y0 >= -1 && y0 < Hh - 1) ? 1.f : 0.f;
        float vx0 = (x0 >= 0  && x0 < Ww)     ? 1.f : 0.f;
        float vx1 = (x0 >= -1 && x0 < Ww - 1) ? 1.f : 0.f;
        int y0c = min(max(y0, 0), Hh - 1);
        int y1c = min(max(y0 + 1, 0), Hh - 1);
        int x0c = min(max(x0, 0), Ww - 1);
        int x1c = min(max(x0 + 1, 0), Ww - 1);
        float w00 = (1.f - wy) * (1.f - wx) * m * vy0 * vx0;
        float w01 = (1.f - wy) * wx         * m * vy0 * vx1;
        float w10 = wy         * (1.f - wx) * m * vy1 * vx0;
        float w11 = wy         * wx         * m * vy1 * vx1;
        const float* p00 = xTb + (y0c * Ww + x0c) * 64 + wid * 16;
        const float* p01 = xTb + (y0c * Ww + x1c) * 64 + wid * 16;
        const float* p10 = xTb + (y1c * Ww + x0c) * 64 + wid * 16;
        const float* p11 = xTb + (y1c * Ww + x1c) * 64 + wid * 16;
#pragma unroll
        for (int cg = 0; cg < 4; ++cg) {
            float4 v00 = *reinterpret_cast<const float4*>(p00 + 4 * cg);
            float4 v01 = *reinterpret_cast<const float4*>(p01 + 4 * cg);
            float4 v10 = *reinterpret_cast<const float4*>(p10 + 4 * cg);
            float4 v11 = *reinterpret_cast<const float4*>(p11 + 4 * cg);
            float s0 = w00 * v00.x + w01 * v01.x;
            s0 = fmaf(w10, v10.x, s0); s0 = fmaf(w11, v11.x, s0);
            float s1 = w00 * v00.y + w01 * v01.y;
            s1 = fmaf(w10, v10.y, s1); s1 = fmaf(w11, v11.y, s1);
            float s2 = w00 * v00.z + w01 * v01.z;
            s2 = fmaf(w10, v10.z, s2); s2 = fmaf(w11, v11.z, s2);
            float s3 = w00 * v00.w + w01 * v01.w;
            s3 = fmaf(w10, v10.w, s3); s3 = fmaf(w11, v11.w, s3);
            unsigned int hp0, lp0, hp1, lp1;
            split2(s0, s1, hp0, lp0);
            split2(s2, s3, hp1, lp1);
            int cp = 8 * wid + 2 * cg;     // cin pair row
            lds[buf][0][(cp    ) * 64 + lane] = hp0;
            lds[buf][0][(cp + 1) * 64 + lane] = hp1;
            lds[buf][1][(cp    ) * 64 + lane] = lp0;
            lds[buf][1][(cp + 1) * 64 + lane] = lp1;
        }
    };

    f32x4 acc[4];
#pragma unroll
    for (int t = 0; t < 4; ++t) acc[t] = {0.f, 0.f, 0.f, 0.f};

    SAMPLE(0, 0);
    __syncthreads();

    for (int k = 0; k < 9; ++k) {
        int cur = k & 1;
        if (k < 8) SAMPLE(k + 1, cur ^ 1);
        const bf16x8* waH = reinterpret_cast<const bf16x8*>(
            wA_hi + ((k * 4 + wid) * 2) * 512 + lane * 8);
        const bf16x8* waL = reinterpret_cast<const bf16x8*>(
            wA_lo + ((k * 4 + wid) * 2) * 512 + lane * 8);
        bf16x8 a0h = waH[0], a1h = waH[64];
        bf16x8 a0l = waL[0], a1l = waL[64];
        const unsigned int* Lh = &lds[cur][0][0];
        const unsigned int* Ll = &lds[cur][1][0];
        int g4 = (lane >> 4) * 4;
#pragma unroll
        for (int t = 0; t < 4; ++t) {
            int colp = 16 * t + (lane & 15);
            bf16x8 b0h = mk8(Lh[(g4 + 0) * 64 + colp], Lh[(g4 + 1) * 64 + colp],
                             Lh[(g4 + 2) * 64 + colp], Lh[(g4 + 3) * 64 + colp]);
            bf16x8 b1h = mk8(Lh[(16 + g4 + 0) * 64 + colp], Lh[(16 + g4 + 1) * 64 + colp],
                             Lh[(16 + g4 + 2) * 64 + colp], Lh[(16 + g4 + 3) * 64 + colp]);
            bf16x8 b0l = mk8(Ll[(g4 + 0) * 64 + colp], Ll[(g4 + 1) * 64 + colp],
                             Ll[(g4 + 2) * 64 + colp], Ll[(g4 + 3) * 64 + colp]);
            bf16x8 b1l = mk8(Ll[(16 + g4 + 0) * 64 + colp], Ll[(16 + g4 + 1) * 64 + colp],
                             Ll[(16 + g4 + 2) * 64 + colp], Ll[(16 + g4 + 3) * 64 + colp]);
            acc[t] = __builtin_amdgcn_mfma_f32_16x16x32_bf16(a0h, b0h, acc[t], 0, 0, 0);
            acc[t] = __builtin_amdgcn_mfma_f32_16x16x32_bf16(a0l, b0h, acc[t], 0, 0, 0);
            acc[t] = __builtin_amdgcn_mfma_f32_16x16x32_bf16(a0h, b0l, acc[t], 0, 0, 0);
            acc[t] = __builtin_amdgcn_mfma_f32_16x16x32_bf16(a1h, b1h, acc[t], 0, 0, 0);
            acc[t] = __builtin_amdgcn_mfma_f32_16x16x32_bf16(a1l, b1h, acc[t], 0, 0, 0);
            acc[t] = __builtin_amdgcn_mfma_f32_16x16x32_bf16(a1h, b1l, acc[t], 0, 0, 0);
        }
        __syncthreads();
    }

#pragma unroll
    for (int t = 0; t < 4; ++t) {
        int p2 = wg * 64 + 16 * t + (lane & 15);
        if (p2 >= Npix) continue;
        int b2 = p2 / PixPerImg;
        int r2 = p2 - b2 * PixPerImg;
        int ho2 = r2 / Wo;
        int wo2 = r2 - ho2 * Wo;
#pragma unroll
        for (int rg = 0; rg < 4; ++rg) {
            int cout = 16 * wid + 4 * (lane >> 4) + rg;
            float v = acc[t][rg] + bias[cout];
            out[((b2 * Cout + cout) * Ho + ho2) * Wo + wo2] = fmaxf(v, 0.f);
        }
    }
}

extern "C" void kernel_launch(void* const* d_in, const int* in_sizes, int n_in,
                              void* d_out, int out_size, void* d_ws, size_t ws_size,
                              hipStream_t stream)
{
    const float* x      = (const float*)d_in[0];
    const float* w_off  = (const float*)d_in[1];
    const float* b_off  = (const float*)d_in[2];
    const float* weight = (const float*)d_in[3];
    const float* bias   = (const float*)d_in[4];

    float* A_conv = (float*)d_ws;                               // 27*Npix f32
    float* xT     = A_conv + 27 * Npix;                         // 4*HW*64 f32
    unsigned short* wA_hi   = (unsigned short*)(xT + (size_t)Bn * HW * 64);
    unsigned short* wA_lo   = wA_hi + 36864;
    unsigned short* wOff_hi = wA_lo + 36864;
    unsigned short* wOff_lo = wOff_hi + 36864;

    prep_kernel<<<144, 256, 0, stream>>>(w_off, weight, wA_hi, wA_lo,
                                         wOff_hi, wOff_lo);
    transpose_kernel<<<Bn * (HW / 64), 256, 0, stream>>>(x, xT);
    offconv_mfma<<<NWG, 256, 0, stream>>>(x, wOff_hi, wOff_lo, A_conv);
    fused_mfma<<<NWG, 256, 0, stream>>>(xT, A_conv, b_off, wA_hi, wA_lo, bias,
                                        (float*)d_out);
}

// Round 10
// 112.133 us; speedup vs baseline: 4.2021x; 1.0594x over previous
//
#include <hip/hip_runtime.h>
#include <hip/hip_bf16.h>
#include <math.h>

namespace {
constexpr int Bn = 4, Cin = 64, Cout = 64, Hh = 128, Ww = 128, Ho = 126, Wo = 126;
constexpr int Npix = Bn * Ho * Wo;          // 63504
constexpr int HW = Hh * Ww;                 // 16384
constexpr int PixPerImg = Ho * Wo;          // 15876
constexpr int NWG = (Npix + 63) / 64;       // 993 blocks (64 px each)
constexpr int ROWU = 68;                    // LDS row stride (uints): 64 + 4 pad
}

typedef __attribute__((ext_vector_type(8))) short bf16x8;
typedef __attribute__((ext_vector_type(4))) float f32x4;

__device__ __forceinline__ unsigned short f2bf(float f) {
    __hip_bfloat16 h = __float2bfloat16(f);
    return __builtin_bit_cast(unsigned short, h);
}
__device__ __forceinline__ float bf2f(unsigned short u) {
    unsigned int v = (unsigned int)u << 16;
    return __builtin_bit_cast(float, v);
}
__device__ __forceinline__ unsigned int f2bf_pk(float lo, float hi) {
    return (unsigned int)f2bf(lo) | ((unsigned int)f2bf(hi) << 16);
}
__device__ __forceinline__ bf16x8 mk8(unsigned int u0, unsigned int u1,
                                      unsigned int u2, unsigned int u3) {
    union { unsigned int u[4]; bf16x8 v; } x;
    x.u[0] = u0; x.u[1] = u1; x.u[2] = u2; x.u[3] = u3;
    return x.v;
}
// bijective XCD swizzle (m204): contiguous chunk of blocks per XCD
__device__ __forceinline__ int swz_block(int orig, int nwg) {
    int q = nwg >> 3, r = nwg & 7;
    int xcd = orig & 7, idx = orig >> 3;
    return (xcd < r ? xcd * (q + 1) : r * (q + 1) + (xcd - r) * q) + idx;
}

// ---------------------------------------------------------------------------
// prep: hi/lo bf16 A-fragment streams, PROVEN mapping (R6/R8). Weights stay
// split (hi+lo); samples will be plain bf16.
// ---------------------------------------------------------------------------
__global__ __launch_bounds__(256) void prep_kernel(
    const float* __restrict__ w_off, const float* __restrict__ weight,
    unsigned short* __restrict__ wA_hi, unsigned short* __restrict__ wA_lo,
    unsigned short* __restrict__ wOff_hi, unsigned short* __restrict__ wOff_lo)
{
    int i = blockIdx.x * 256 + threadIdx.x;
    if (i < 36864) {
        int j = i % 8;  int t = i / 8;
        int l = t % 64; t /= 64;
        int h = t % 2;  t /= 2;
        int w = t % 4;  int k = t / 4;
        int cout = 16 * w + (l & 15);
        int cin  = 32 * h + 8 * (l >> 4) + j;
        float v = weight[cout * 576 + cin * 9 + k];
        unsigned short hi = f2bf(v);
        wA_hi[i] = hi;
        wA_lo[i] = f2bf(v - bf2f(hi));

        int o = cout;   // same index domain, zero-padded past 27
        float vo = o < 27 ? w_off[o * 576 + cin * 9 + k] : 0.f;
        unsigned short oh = f2bf(vo);
        wOff_hi[i] = oh;
        wOff_lo[i] = f2bf(vo - bf2f(oh));
    }
}

// ---------------------------------------------------------------------------
// NCHW -> NHWC transpose: xT[(b*HW + hw)*64 + c] = x[b][c][hw].
// ---------------------------------------------------------------------------
__global__ __launch_bounds__(256) void transpose_kernel(
    const float* __restrict__ x, float* __restrict__ xT)
{
    __shared__ float t[64][65];
    int blk  = blockIdx.x;
    int b    = blk >> 8;                 // HW/64 = 256 chunks per image
    int hw0  = (blk & 255) * 64;
    int lane = (int)(threadIdx.x & 63);
    int w4   = (int)(threadIdx.x >> 6);  // 0..3

    const float* xb = x + b * (Cin * HW) + hw0;
#pragma unroll
    for (int i = 0; i < 16; ++i) {
        int cin = w4 * 16 + i;
        t[cin][lane] = xb[cin * HW + lane];
    }
    __syncthreads();
    float* dst = xT + (b * HW + hw0) * 64;
#pragma unroll
    for (int i = 0; i < 16; ++i) {
        int px = w4 * 16 + i;
        dst[px * 64 + lane] = t[lane][px];
    }
}

// ---------------------------------------------------------------------------
// offset conv (3x3 VALID, 64->27) via MFMA. Samples plain bf16 (hi only),
// weights split hi/lo. LDS stride 68 (conflict-free reads). Scalar LDS only.
// ---------------------------------------------------------------------------
__global__ __launch_bounds__(256, 4) void offconv_mfma(
    const float* __restrict__ x, const unsigned short* __restrict__ wOff_hi,
    const unsigned short* __restrict__ wOff_lo, float* __restrict__ A_conv)
{
    __shared__ unsigned int lds[2][32 * ROWU];   // 17.4 KB

    int wg   = swz_block(blockIdx.x, NWG);
    int wid  = __builtin_amdgcn_readfirstlane((int)(threadIdx.x >> 6));
    int lane = (int)(threadIdx.x & 63);
    int p  = wg * 64 + lane;
    int pc = p < Npix ? p : (Npix - 1);
    int b  = pc / PixPerImg;
    int r  = pc - b * PixPerImg;
    int ho = r / Wo;
    int wo = r - ho * Wo;

    const float* xb = x + b * (Cin * HW) + ho * Ww + wo;

    auto STAGE = [&](int k, int buf) {
        int kh = k / 3, kw = k - 3 * kh;
        const float* base = xb + kh * Ww + kw;
#pragma unroll
        for (int pr = 0; pr < 8; ++pr) {
            float s0 = base[(wid * 16 + 2 * pr) * HW];
            float s1 = base[(wid * 16 + 2 * pr + 1) * HW];
            lds[buf][(8 * wid + pr) * ROWU + lane] = f2bf_pk(s0, s1);
        }
    };

    f32x4 acc[4];
#pragma unroll
    for (int t = 0; t < 4; ++t) acc[t] = {0.f, 0.f, 0.f, 0.f};

    STAGE(0, 0);
    __syncthreads();

    for (int k = 0; k < 9; ++k) {
        int cur = k & 1;
        if (k < 8) STAGE(k + 1, cur ^ 1);
        if (wid < 2) {
            const bf16x8* waH = reinterpret_cast<const bf16x8*>(
                wOff_hi + ((k * 4 + wid) * 2) * 512 + lane * 8);
            const bf16x8* waL = reinterpret_cast<const bf16x8*>(
                wOff_lo + ((k * 4 + wid) * 2) * 512 + lane * 8);
            bf16x8 a0h = waH[0], a1h = waH[64];
            bf16x8 a0l = waL[0], a1l = waL[64];
            const unsigned int* Lh = &lds[cur][0];
            int g4 = (lane >> 4) * 4;
#pragma unroll
            for (int t = 0; t < 4; ++t) {
                int colp = 16 * t + (lane & 15);
                bf16x8 b0 = mk8(Lh[(g4 + 0) * ROWU + colp], Lh[(g4 + 1) * ROWU + colp],
                                Lh[(g4 + 2) * ROWU + colp], Lh[(g4 + 3) * ROWU + colp]);
                bf16x8 b1 = mk8(Lh[(16 + g4 + 0) * ROWU + colp], Lh[(16 + g4 + 1) * ROWU + colp],
                                Lh[(16 + g4 + 2) * ROWU + colp], Lh[(16 + g4 + 3) * ROWU + colp]);
                acc[t] = __builtin_amdgcn_mfma_f32_16x16x32_bf16(a0h, b0, acc[t], 0, 0, 0);
                acc[t] = __builtin_amdgcn_mfma_f32_16x16x32_bf16(a0l, b0, acc[t], 0, 0, 0);
                acc[t] = __builtin_amdgcn_mfma_f32_16x16x32_bf16(a1h, b1, acc[t], 0, 0, 0);
                acc[t] = __builtin_amdgcn_mfma_f32_16x16x32_bf16(a1l, b1, acc[t], 0, 0, 0);
            }
        }
        __syncthreads();
    }

    if (wid < 2) {
#pragma unroll
        for (int t = 0; t < 4; ++t) {
            int p2 = wg * 64 + 16 * t + (lane & 15);
            if (p2 >= Npix) continue;
#pragma unroll
            for (int rg = 0; rg < 4; ++rg) {
                int o = 16 * wid + 4 * (lane >> 4) + rg;
                if (o < 27) A_conv[o * Npix + p2] = acc[t][rg];
            }
        }
    }
}

// ---------------------------------------------------------------------------
// fused bilinear sample + main conv via MFMA. Samples plain bf16 (hi only),
// weights split hi/lo. NHWC float4 gathers. LDS stride 68, scalar-only.
// ---------------------------------------------------------------------------
__global__ __launch_bounds__(256, 4) void fused_mfma(
    const float* __restrict__ xT, const float* __restrict__ A_conv,
    const float* __restrict__ b_off, const unsigned short* __restrict__ wA_hi,
    const unsigned short* __restrict__ wA_lo, const float* __restrict__ bias,
    float* __restrict__ out)
{
    __shared__ unsigned int lds[2][32 * ROWU];   // 17.4 KB

    int wg   = swz_block(blockIdx.x, NWG);
    int wid  = __builtin_amdgcn_readfirstlane((int)(threadIdx.x >> 6));
    int lane = (int)(threadIdx.x & 63);
    int p  = wg * 64 + lane;
    int pc = p < Npix ? p : (Npix - 1);
    int b  = pc / PixPerImg;
    int r  = pc - b * PixPerImg;
    int ho = r / Wo;
    int wo = r - ho * Wo;

    const float* xTb = xT + (size_t)b * HW * 64;

    auto SAMPLE = [&](int k, int buf) {
        float oy = A_conv[(2 * k) * Npix + pc];
        float ox = A_conv[(2 * k + 1) * Npix + pc];
        float mv = A_conv[(18 + k) * Npix + pc] + b_off[18 + k];
        float ys = (float)(ho + k / 3) + oy + b_off[2 * k];
        float xs = (float)(wo + k % 3) + ox + b_off[2 * k + 1];
        float m  = 1.0f / (1.0f + expf(-mv));
        float y0f = floorf(ys), x0f = floorf(xs);
        float wy = ys - y0f, wx = xs - x0f;
        int y0 = (int)y0f, x0 = (int)x0f;
        float vy0 = (y0 >= 0  && y0 < Hh)     ? 1.f : 0.f;
        float vy1 = (y0 >= -1 && y0 < Hh - 1) ? 1.f : 0.f;
        float vx0 = (x0 >= 0  && x0 < Ww)     ? 1.f : 0.f;
        float vx1 = (x0 >= -1 && x0 < Ww - 1) ? 1.f : 0.f;
        int y0c = min(max(y0, 0), Hh - 1);
        int y1c = min(max(y0 + 1, 0), Hh - 1);
        int x0c = min(max(x0, 0), Ww - 1);
        int x1c = min(max(x0 + 1, 0), Ww - 1);
        float w00 = (1.f - wy) * (1.f - wx) * m * vy0 * vx0;
        float w01 = (1.f - wy) * wx         * m * vy0 * vx1;
        float w10 = wy         * (1.f - wx) * m * vy1 * vx0;
        float w11 = wy         * wx         * m * vy1 * vx1;
        const float* p00 = xTb + (y0c * Ww + x0c) * 64 + wid * 16;
        const float* p01 = xTb + (y0c * Ww + x1c) * 64 + wid * 16;
        const float* p10 = xTb + (y1c * Ww + x0c) * 64 + wid * 16;
        const float* p11 = xTb + (y1c * Ww + x1c) * 64 + wid * 16;
#pragma unroll
        for (int cg = 0; cg < 4; ++cg) {
            float4 v00 = *reinterpret_cast<const float4*>(p00 + 4 * cg);
            float4 v01 = *reinterpret_cast<const float4*>(p01 + 4 * cg);
            float4 v10 = *reinterpret_cast<const float4*>(p10 + 4 * cg);
            float4 v11 = *reinterpret_cast<const float4*>(p11 + 4 * cg);
            float s0 = w00 * v00.x + w01 * v01.x;
            s0 = fmaf(w10, v10.x, s0); s0 = fmaf(w11, v11.x, s0);
            float s1 = w00 * v00.y + w01 * v01.y;
            s1 = fmaf(w10, v10.y, s1); s1 = fmaf(w11, v11.y, s1);
            float s2 = w00 * v00.z + w01 * v01.z;
            s2 = fmaf(w10, v10.z, s2); s2 = fmaf(w11, v11.z, s2);
            float s3 = w00 * v00.w + w01 * v01.w;
            s3 = fmaf(w10, v10.w, s3); s3 = fmaf(w11, v11.w, s3);
            int cp = 8 * wid + 2 * cg;     // cin pair row
            lds[buf][(cp    ) * ROWU + lane] = f2bf_pk(s0, s1);
            lds[buf][(cp + 1) * ROWU + lane] = f2bf_pk(s2, s3);
        }
    };

    f32x4 acc[4];
#pragma unroll
    for (int t = 0; t < 4; ++t) acc[t] = {0.f, 0.f, 0.f, 0.f};

    SAMPLE(0, 0);
    __syncthreads();

    for (int k = 0; k < 9; ++k) {
        int cur = k & 1;
        if (k < 8) SAMPLE(k + 1, cur ^ 1);
        const bf16x8* waH = reinterpret_cast<const bf16x8*>(
            wA_hi + ((k * 4 + wid) * 2) * 512 + lane * 8);
        const bf16x8* waL = reinterpret_cast<const bf16x8*>(
            wA_lo + ((k * 4 + wid) * 2) * 512 + lane * 8);
        bf16x8 a0h = waH[0], a1h = waH[64];
        bf16x8 a0l = waL[0], a1l = waL[64];
        const unsigned int* Lh = &lds[cur][0];
        int g4 = (lane >> 4) * 4;
#pragma unroll
        for (int t = 0; t < 4; ++t) {
            int colp = 16 * t + (lane & 15);
            bf16x8 b0 = mk8(Lh[(g4 + 0) * ROWU + colp], Lh[(g4 + 1) * ROWU + colp],
                            Lh[(g4 + 2) * ROWU + colp], Lh[(g4 + 3) * ROWU + colp]);
            bf16x8 b1 = mk8(Lh[(16 + g4 + 0) * ROWU + colp], Lh[(16 + g4 + 1) * ROWU + colp],
                            Lh[(16 + g4 + 2) * ROWU + colp], Lh[(16 + g4 + 3) * ROWU + colp]);
            acc[t] = __builtin_amdgcn_mfma_f32_16x16x32_bf16(a0h, b0, acc[t], 0, 0, 0);
            acc[t] = __builtin_amdgcn_mfma_f32_16x16x32_bf16(a0l, b0, acc[t], 0, 0, 0);
            acc[t] = __builtin_amdgcn_mfma_f32_16x16x32_bf16(a1h, b1, acc[t], 0, 0, 0);
            acc[t] = __builtin_amdgcn_mfma_f32_16x16x32_bf16(a1l, b1, acc[t], 0, 0, 0);
        }
        __syncthreads();
    }

#pragma unroll
    for (int t = 0; t < 4; ++t) {
        int p2 = wg * 64 + 16 * t + (lane & 15);
        if (p2 >= Npix) continue;
        int b2 = p2 / PixPerImg;
        int r2 = p2 - b2 * PixPerImg;
        int ho2 = r2 / Wo;
        int wo2 = r2 - ho2 * Wo;
#pragma unroll
        for (int rg = 0; rg < 4; ++rg) {
            int cout = 16 * wid + 4 * (lane >> 4) + rg;
            float v = acc[t][rg] + bias[cout];
            out[((b2 * Cout + cout) * Ho + ho2) * Wo + wo2] = fmaxf(v, 0.f);
        }
    }
}

extern "C" void kernel_launch(void* const* d_in, const int* in_sizes, int n_in,
                              void* d_out, int out_size, void* d_ws, size_t ws_size,
                              hipStream_t stream)
{
    const float* x      = (const float*)d_in[0];
    const float* w_off  = (const float*)d_in[1];
    const float* b_off  = (const float*)d_in[2];
    const float* weight = (const float*)d_in[3];
    const float* bias   = (const float*)d_in[4];

    float* A_conv = (float*)d_ws;                               // 27*Npix f32
    float* xT     = A_conv + 27 * Npix;                         // 4*HW*64 f32
    unsigned short* wA_hi   = (unsigned short*)(xT + (size_t)Bn * HW * 64);
    unsigned short* wA_lo   = wA_hi + 36864;
    unsigned short* wOff_hi = wA_lo + 36864;
    unsigned short* wOff_lo = wOff_hi + 36864;

    prep_kernel<<<144, 256, 0, stream>>>(w_off, weight, wA_hi, wA_lo,
                                         wOff_hi, wOff_lo);
    transpose_kernel<<<Bn * (HW / 64), 256, 0, stream>>>(x, xT);
    offconv_mfma<<<NWG, 256, 0, stream>>>(x, wOff_hi, wOff_lo, A_conv);
    fused_mfma<<<NWG, 256, 0, stream>>>(xT, A_conv, b_off, wA_hi, wA_lo, bias,
                                        (float*)d_out);
}

// Round 11
// 76.614 us; speedup vs baseline: 6.1503x; 1.4636x over previous
//
#include <hip/hip_runtime.h>
#include <hip/hip_bf16.h>
#include <math.h>

namespace {
constexpr int Bn = 4, Cin = 64, Cout = 64, Hh = 128, Ww = 128, Ho = 126, Wo = 126;
constexpr int Npix = Bn * Ho * Wo;          // 63504
constexpr int HW = Hh * Ww;                 // 16384
constexpr int PixPerImg = Ho * Wo;          // 15876
constexpr int NWG = (Npix + 63) / 64;       // 993 blocks (64 px each)
constexpr int ROWU = 68;                    // LDS row stride (uints): 64 + 4 pad
}

typedef __attribute__((ext_vector_type(8))) short bf16x8;
typedef __attribute__((ext_vector_type(4))) float f32x4;

__device__ __forceinline__ unsigned short f2bf(float f) {
    __hip_bfloat16 h = __float2bfloat16(f);
    return __builtin_bit_cast(unsigned short, h);
}
__device__ __forceinline__ float bf2f(unsigned short u) {
    unsigned int v = (unsigned int)u << 16;
    return __builtin_bit_cast(float, v);
}
__device__ __forceinline__ unsigned int f2bf_pk(float lo, float hi) {
    return (unsigned int)f2bf(lo) | ((unsigned int)f2bf(hi) << 16);
}
__device__ __forceinline__ bf16x8 mk8(unsigned int u0, unsigned int u1,
                                      unsigned int u2, unsigned int u3) {
    union { unsigned int u[4]; bf16x8 v; } x;
    x.u[0] = u0; x.u[1] = u1; x.u[2] = u2; x.u[3] = u3;
    return x.v;
}
// bijective XCD swizzle (m204): contiguous chunk of blocks per XCD
__device__ __forceinline__ int swz_block(int orig, int nwg) {
    int q = nwg >> 3, r = nwg & 7;
    int xcd = orig & 7, idx = orig >> 3;
    return (xcd < r ? xcd * (q + 1) : r * (q + 1) + (xcd - r) * q) + idx;
}

// ---------------------------------------------------------------------------
// prep: hi/lo bf16 A-fragment streams, PROVEN mapping (R6/R8).
// ---------------------------------------------------------------------------
__global__ __launch_bounds__(256) void prep_kernel(
    const float* __restrict__ w_off, const float* __restrict__ weight,
    unsigned short* __restrict__ wA_hi, unsigned short* __restrict__ wA_lo,
    unsigned short* __restrict__ wOff_hi, unsigned short* __restrict__ wOff_lo)
{
    int i = blockIdx.x * 256 + threadIdx.x;
    if (i < 36864) {
        int j = i % 8;  int t = i / 8;
        int l = t % 64; t /= 64;
        int h = t % 2;  t /= 2;
        int w = t % 4;  int k = t / 4;
        int cout = 16 * w + (l & 15);
        int cin  = 32 * h + 8 * (l >> 4) + j;
        float v = weight[cout * 576 + cin * 9 + k];
        unsigned short hi = f2bf(v);
        wA_hi[i] = hi;
        wA_lo[i] = f2bf(v - bf2f(hi));

        int o = cout;   // same index domain, zero-padded past 27
        float vo = o < 27 ? w_off[o * 576 + cin * 9 + k] : 0.f;
        unsigned short oh = f2bf(vo);
        wOff_hi[i] = oh;
        wOff_lo[i] = f2bf(vo - bf2f(oh));
    }
}

// ---------------------------------------------------------------------------
// NCHW f32 -> NHWC bf16-packed transpose:
//   xT16[(b*HW + hw)*32 + cp] = pack(bf16(x[b][2cp][hw]), bf16(x[b][2cp+1][hw]))
// ---------------------------------------------------------------------------
__global__ __launch_bounds__(256) void transpose_kernel(
    const float* __restrict__ x, unsigned int* __restrict__ xT16)
{
    __shared__ float t[64][65];
    int blk  = blockIdx.x;
    int b    = blk >> 8;                 // HW/64 = 256 chunks per image
    int hw0  = (blk & 255) * 64;
    int lane = (int)(threadIdx.x & 63);
    int w4   = (int)(threadIdx.x >> 6);  // 0..3

    const float* xb = x + b * (Cin * HW) + hw0;
#pragma unroll
    for (int i = 0; i < 16; ++i) {
        int cin = w4 * 16 + i;
        t[cin][lane] = xb[cin * HW + lane];
    }
    __syncthreads();
    unsigned int* dst = xT16 + ((size_t)b * HW + hw0) * 32;
    int px = (int)(threadIdx.x >> 2);
    int c8 = (int)(threadIdx.x & 3) * 8;
#pragma unroll
    for (int i = 0; i < 8; ++i) {
        int cp = c8 + i;
        dst[px * 32 + cp] = f2bf_pk(t[2 * cp][px], t[2 * cp + 1][px]);
    }
}

// ---------------------------------------------------------------------------
// offset conv (3x3 VALID, 64->27) via MFMA. Samples bf16 straight from xT16
// (2 uint4 loads/lane/k, already packed). Weights split hi/lo. LDS stride 68.
// ---------------------------------------------------------------------------
__global__ __launch_bounds__(256, 4) void offconv_mfma(
    const unsigned int* __restrict__ xT16,
    const unsigned short* __restrict__ wOff_hi,
    const unsigned short* __restrict__ wOff_lo, float* __restrict__ A_conv)
{
    __shared__ unsigned int lds[2][32 * ROWU];   // 17.4 KB

    int wg   = swz_block(blockIdx.x, NWG);
    int wid  = __builtin_amdgcn_readfirstlane((int)(threadIdx.x >> 6));
    int lane = (int)(threadIdx.x & 63);
    int p  = wg * 64 + lane;
    int pc = p < Npix ? p : (Npix - 1);
    int b  = pc / PixPerImg;
    int r  = pc - b * PixPerImg;
    int ho = r / Wo;
    int wo = r - ho * Wo;

    const unsigned int* xb = xT16 + ((size_t)b * HW + ho * Ww + wo) * 32 + wid * 8;

    auto STAGE = [&](int k, int buf) {
        int kh = k / 3, kw = k - 3 * kh;
        const unsigned int* base = xb + (kh * Ww + kw) * 32;
        uint4 qa = *reinterpret_cast<const uint4*>(base);
        uint4 qb = *reinterpret_cast<const uint4*>(base + 4);
        unsigned int* dst = &lds[buf][(8 * wid) * ROWU + lane];
        dst[0 * ROWU] = qa.x; dst[1 * ROWU] = qa.y;
        dst[2 * ROWU] = qa.z; dst[3 * ROWU] = qa.w;
        dst[4 * ROWU] = qb.x; dst[5 * ROWU] = qb.y;
        dst[6 * ROWU] = qb.z; dst[7 * ROWU] = qb.w;
    };

    f32x4 acc[4];
#pragma unroll
    for (int t = 0; t < 4; ++t) acc[t] = {0.f, 0.f, 0.f, 0.f};

    STAGE(0, 0);
    __syncthreads();

    for (int k = 0; k < 9; ++k) {
        int cur = k & 1;
        if (k < 8) STAGE(k + 1, cur ^ 1);
        if (wid < 2) {
            const bf16x8* waH = reinterpret_cast<const bf16x8*>(
                wOff_hi + ((k * 4 + wid) * 2) * 512 + lane * 8);
            const bf16x8* waL = reinterpret_cast<const bf16x8*>(
                wOff_lo + ((k * 4 + wid) * 2) * 512 + lane * 8);
            bf16x8 a0h = waH[0], a1h = waH[64];
            bf16x8 a0l = waL[0], a1l = waL[64];
            const unsigned int* Lh = &lds[cur][0];
            int g4 = (lane >> 4) * 4;
#pragma unroll
            for (int t = 0; t < 4; ++t) {
                int colp = 16 * t + (lane & 15);
                bf16x8 b0 = mk8(Lh[(g4 + 0) * ROWU + colp], Lh[(g4 + 1) * ROWU + colp],
                                Lh[(g4 + 2) * ROWU + colp], Lh[(g4 + 3) * ROWU + colp]);
                bf16x8 b1 = mk8(Lh[(16 + g4 + 0) * ROWU + colp], Lh[(16 + g4 + 1) * ROWU + colp],
                                Lh[(16 + g4 + 2) * ROWU + colp], Lh[(16 + g4 + 3) * ROWU + colp]);
                acc[t] = __builtin_amdgcn_mfma_f32_16x16x32_bf16(a0h, b0, acc[t], 0, 0, 0);
                acc[t] = __builtin_amdgcn_mfma_f32_16x16x32_bf16(a0l, b0, acc[t], 0, 0, 0);
                acc[t] = __builtin_amdgcn_mfma_f32_16x16x32_bf16(a1h, b1, acc[t], 0, 0, 0);
                acc[t] = __builtin_amdgcn_mfma_f32_16x16x32_bf16(a1l, b1, acc[t], 0, 0, 0);
            }
        }
        __syncthreads();
    }

    if (wid < 2) {
#pragma unroll
        for (int t = 0; t < 4; ++t) {
            int p2 = wg * 64 + 16 * t + (lane & 15);
            if (p2 >= Npix) continue;
#pragma unroll
            for (int rg = 0; rg < 4; ++rg) {
                int o = 16 * wid + 4 * (lane >> 4) + rg;
                if (o < 27) A_conv[o * Npix + p2] = acc[t][rg];
            }
        }
    }
}

// ---------------------------------------------------------------------------
// fused bilinear sample + main conv via MFMA. Gathers bf16-packed xT16:
// per corner 2 uint4 loads (16 cins); bilinear in f32 after unpack; samples
// bf16 in LDS (stride 68, scalar stores). Weights split hi/lo.
// ---------------------------------------------------------------------------
__global__ __launch_bounds__(256, 4) void fused_mfma(
    const unsigned int* __restrict__ xT16, const float* __restrict__ A_conv,
    const float* __restrict__ b_off, const unsigned short* __restrict__ wA_hi,
    const unsigned short* __restrict__ wA_lo, const float* __restrict__ bias,
    float* __restrict__ out)
{
    __shared__ unsigned int lds[2][32 * ROWU];   // 17.4 KB

    int wg   = swz_block(blockIdx.x, NWG);
    int wid  = __builtin_amdgcn_readfirstlane((int)(threadIdx.x >> 6));
    int lane = (int)(threadIdx.x & 63);
    int p  = wg * 64 + lane;
    int pc = p < Npix ? p : (Npix - 1);
    int b  = pc / PixPerImg;
    int r  = pc - b * PixPerImg;
    int ho = r / Wo;
    int wo = r - ho * Wo;

    const unsigned int* xTb = xT16 + (size_t)b * HW * 32 + wid * 8;

    auto SAMPLE = [&](int k, int buf) {
        float oy = A_conv[(2 * k) * Npix + pc];
        float ox = A_conv[(2 * k + 1) * Npix + pc];
        float mv = A_conv[(18 + k) * Npix + pc] + b_off[18 + k];
        float ys = (float)(ho + k / 3) + oy + b_off[2 * k];
        float xs = (float)(wo + k % 3) + ox + b_off[2 * k + 1];
        float m  = 1.0f / (1.0f + expf(-mv));
        float y0f = floorf(ys), x0f = floorf(xs);
        float wy = ys - y0f, wx = xs - x0f;
        int y0 = (int)y0f, x0 = (int)x0f;
        float vy0 = (y0 >= 0  && y0 < Hh)     ? 1.f : 0.f;
        float vy1 = (y0 >= -1 && y0 < Hh - 1) ? 1.f : 0.f;
        float vx0 = (x0 >= 0  && x0 < Ww)     ? 1.f : 0.f;
        float vx1 = (x0 >= -1 && x0 < Ww - 1) ? 1.f : 0.f;
        int y0c = min(max(y0, 0), Hh - 1);
        int y1c = min(max(y0 + 1, 0), Hh - 1);
        int x0c = min(max(x0, 0), Ww - 1);
        int x1c = min(max(x0 + 1, 0), Ww - 1);
        float w00 = (1.f - wy) * (1.f - wx) * m * vy0 * vx0;
        float w01 = (1.f - wy) * wx         * m * vy0 * vx1;
        float w10 = wy         * (1.f - wx) * m * vy1 * vx0;
        float w11 = wy         * wx         * m * vy1 * vx1;
        const unsigned int* p00 = xTb + (y0c * Ww + x0c) * 32;
        const unsigned int* p01 = xTb + (y0c * Ww + x1c) * 32;
        const unsigned int* p10 = xTb + (y1c * Ww + x0c) * 32;
        const unsigned int* p11 = xTb + (y1c * Ww + x1c) * 32;
        uint4 a00 = *reinterpret_cast<const uint4*>(p00);
        uint4 b00 = *reinterpret_cast<const uint4*>(p00 + 4);
        uint4 a01 = *reinterpret_cast<const uint4*>(p01);
        uint4 b01 = *reinterpret_cast<const uint4*>(p01 + 4);
        uint4 a10 = *reinterpret_cast<const uint4*>(p10);
        uint4 b10 = *reinterpret_cast<const uint4*>(p10 + 4);
        uint4 a11 = *reinterpret_cast<const uint4*>(p11);
        uint4 b11 = *reinterpret_cast<const uint4*>(p11 + 4);

        unsigned int* dst = &lds[buf][(8 * wid) * ROWU + lane];
        auto DO = [&](unsigned int u00, unsigned int u01, unsigned int u10,
                      unsigned int u11, int j) {
            float c00a = bf2f((unsigned short)(u00 & 0xffff));
            float c00b = bf2f((unsigned short)(u00 >> 16));
            float c01a = bf2f((unsigned short)(u01 & 0xffff));
            float c01b = bf2f((unsigned short)(u01 >> 16));
            float c10a = bf2f((unsigned short)(u10 & 0xffff));
            float c10b = bf2f((unsigned short)(u10 >> 16));
            float c11a = bf2f((unsigned short)(u11 & 0xffff));
            float c11b = bf2f((unsigned short)(u11 >> 16));
            float s0 = w00 * c00a + w01 * c01a;
            s0 = fmaf(w10, c10a, s0); s0 = fmaf(w11, c11a, s0);
            float s1 = w00 * c00b + w01 * c01b;
            s1 = fmaf(w10, c10b, s1); s1 = fmaf(w11, c11b, s1);
            dst[j * ROWU] = f2bf_pk(s0, s1);
        };
        DO(a00.x, a01.x, a10.x, a11.x, 0);
        DO(a00.y, a01.y, a10.y, a11.y, 1);
        DO(a00.z, a01.z, a10.z, a11.z, 2);
        DO(a00.w, a01.w, a10.w, a11.w, 3);
        DO(b00.x, b01.x, b10.x, b11.x, 4);
        DO(b00.y, b01.y, b10.y, b11.y, 5);
        DO(b00.z, b01.z, b10.z, b11.z, 6);
        DO(b00.w, b01.w, b10.w, b11.w, 7);
    };

    f32x4 acc[4];
#pragma unroll
    for (int t = 0; t < 4; ++t) acc[t] = {0.f, 0.f, 0.f, 0.f};

    SAMPLE(0, 0);
    __syncthreads();

    for (int k = 0; k < 9; ++k) {
        int cur = k & 1;
        if (k < 8) SAMPLE(k + 1, cur ^ 1);
        const bf16x8* waH = reinterpret_cast<const bf16x8*>(
            wA_hi + ((k * 4 + wid) * 2) * 512 + lane * 8);
        const bf16x8* waL = reinterpret_cast<const bf16x8*>(
            wA_lo + ((k * 4 + wid) * 2) * 512 + lane * 8);
        bf16x8 a0h = waH[0], a1h = waH[64];
        bf16x8 a0l = waL[0], a1l = waL[64];
        const unsigned int* Lh = &lds[cur][0];
        int g4 = (lane >> 4) * 4;
#pragma unroll
        for (int t = 0; t < 4; ++t) {
            int colp = 16 * t + (lane & 15);
            bf16x8 b0 = mk8(Lh[(g4 + 0) * ROWU + colp], Lh[(g4 + 1) * ROWU + colp],
                            Lh[(g4 + 2) * ROWU + colp], Lh[(g4 + 3) * ROWU + colp]);
            bf16x8 b1 = mk8(Lh[(16 + g4 + 0) * ROWU + colp], Lh[(16 + g4 + 1) * ROWU + colp],
                            Lh[(16 + g4 + 2) * ROWU + colp], Lh[(16 + g4 + 3) * ROWU + colp]);
            acc[t] = __builtin_amdgcn_mfma_f32_16x16x32_bf16(a0h, b0, acc[t], 0, 0, 0);
            acc[t] = __builtin_amdgcn_mfma_f32_16x16x32_bf16(a0l, b0, acc[t], 0, 0, 0);
            acc[t] = __builtin_amdgcn_mfma_f32_16x16x32_bf16(a1h, b1, acc[t], 0, 0, 0);
            acc[t] = __builtin_amdgcn_mfma_f32_16x16x32_bf16(a1l, b1, acc[t], 0, 0, 0);
        }
        __syncthreads();
    }

#pragma unroll
    for (int t = 0; t < 4; ++t) {
        int p2 = wg * 64 + 16 * t + (lane & 15);
        if (p2 >= Npix) continue;
        int b2 = p2 / PixPerImg;
        int r2 = p2 - b2 * PixPerImg;
        int ho2 = r2 / Wo;
        int wo2 = r2 - ho2 * Wo;
#pragma unroll
        for (int rg = 0; rg < 4; ++rg) {
            int cout = 16 * wid + 4 * (lane >> 4) + rg;
            float v = acc[t][rg] + bias[cout];
            out[((b2 * Cout + cout) * Ho + ho2) * Wo + wo2] = fmaxf(v, 0.f);
        }
    }
}

extern "C" void kernel_launch(void* const* d_in, const int* in_sizes, int n_in,
                              void* d_out, int out_size, void* d_ws, size_t ws_size,
                              hipStream_t stream)
{
    const float* x      = (const float*)d_in[0];
    const float* w_off  = (const float*)d_in[1];
    const float* b_off  = (const float*)d_in[2];
    const float* weight = (const float*)d_in[3];
    const float* bias   = (const float*)d_in[4];

    float* A_conv = (float*)d_ws;                               // 27*Npix f32
    unsigned int* xT16 = (unsigned int*)(A_conv + 27 * Npix);   // Bn*HW*32 uints
    unsigned short* wA_hi   = (unsigned short*)(xT16 + (size_t)Bn * HW * 32);
    unsigned short* wA_lo   = wA_hi + 36864;
    unsigned short* wOff_hi = wA_lo + 36864;
    unsigned short* wOff_lo = wOff_hi + 36864;

    prep_kernel<<<144, 256, 0, stream>>>(w_off, weight, wA_hi, wA_lo,
                                         wOff_hi, wOff_lo);
    transpose_kernel<<<Bn * (HW / 64), 256, 0, stream>>>(x, xT16);
    offconv_mfma<<<NWG, 256, 0, stream>>>(xT16, wOff_hi, wOff_lo, A_conv);
    fused_mfma<<<NWG, 256, 0, stream>>>(xT16, A_conv, b_off, wA_hi, wA_lo, bias,
                                        (float*)d_out);
}